// Round 1
// baseline (5118.382 us; speedup 1.0000x reference)
//
#include <hip/hip_runtime.h>
#include <cstddef>
#include <cstdint>

namespace {

constexpr int Bc = 2, Tc = 2048, Dc = 1024, Hc = 8, Mc = 64, KDc = 128;
constexpr int ROWS = Bc * Tc; // 4096
constexpr float SCALE = 0.08838834764831845f; // 128^-0.5
constexpr float GATE_NORM_INV = 1.0f / 16.0f;

__device__ __forceinline__ float swishf(float x) {
  return x / (1.0f + __expf(-x));
}

// C[i,j] = sum_k A[i,k] * Bw[j,k]; A: MxK, Bw: NxK, C: MxN (all row-major)
// MODE 0: plain, 1: swish, 2: g = log_sigmoid(x)/16
template<int MODE>
__global__ __launch_bounds__(256)
void gemm_nt(const float* __restrict__ A, const float* __restrict__ Bw,
             float* __restrict__ C, int M, int N, int K)
{
  __shared__ __align__(16) float As[16][68]; // [k][row], +4 pad keeps 16B align, fewer bank conflicts
  __shared__ __align__(16) float Bs[16][68];
  const int tid = threadIdx.x;
  const int tx = tid & 15, ty = tid >> 4;
  const int row0 = blockIdx.y * 64, col0 = blockIdx.x * 64;
  const int lr = tid >> 2, lk = (tid & 3) << 2;
  const float* Ap = A + (size_t)(row0 + lr) * K + lk;
  const float* Bp = Bw + (size_t)(col0 + lr) * K + lk;
  float acc[4][4];
#pragma unroll
  for (int r = 0; r < 4; ++r)
#pragma unroll
    for (int c = 0; c < 4; ++c) acc[r][c] = 0.f;

  for (int k0 = 0; k0 < K; k0 += 16) {
    float4 a4 = *(const float4*)(Ap + k0);
    float4 b4 = *(const float4*)(Bp + k0);
    __syncthreads();
    As[lk + 0][lr] = a4.x; As[lk + 1][lr] = a4.y; As[lk + 2][lr] = a4.z; As[lk + 3][lr] = a4.w;
    Bs[lk + 0][lr] = b4.x; Bs[lk + 1][lr] = b4.y; Bs[lk + 2][lr] = b4.z; Bs[lk + 3][lr] = b4.w;
    __syncthreads();
#pragma unroll
    for (int kk = 0; kk < 16; ++kk) {
      float4 av = *(const float4*)&As[kk][ty << 2];
      float4 bv = *(const float4*)&Bs[kk][tx << 2];
      float ar[4] = {av.x, av.y, av.z, av.w};
      float br[4] = {bv.x, bv.y, bv.z, bv.w};
#pragma unroll
      for (int r = 0; r < 4; ++r)
#pragma unroll
        for (int c = 0; c < 4; ++c) acc[r][c] = fmaf(ar[r], br[c], acc[r][c]);
    }
  }
#pragma unroll
  for (int r = 0; r < 4; ++r) {
    size_t off = (size_t)(row0 + (ty << 2) + r) * N + col0 + (tx << 2);
#pragma unroll
    for (int c = 0; c < 4; ++c) {
      float x = acc[r][c];
      if (MODE == 0) {
        C[off + c] = x;
      } else if (MODE == 1) {
        C[off + c] = swishf(x);
      } else {
        // g = log_sigmoid(x) / 16  (stable);  s = 1-exp(g) derived later in scan
        float g = (fminf(x, 0.f) - __logf(1.f + __expf(-fabsf(x)))) * GATE_NORM_INV;
        C[off + c] = g;
      }
    }
  }
}

// One block per (b,h). 512 threads, state in registers:
//  hk[k,m]: thread m*8+kg owns k = kg*16 .. kg*16+15   (16 regs)
//  hv[m,v]: thread v*4+mg owns m = mg*16 .. mg*16+15   (16 regs)
__global__ __launch_bounds__(512)
void scan_kernel(const float* __restrict__ Q, const float* __restrict__ Kt,
                 const float* __restrict__ V, const float* __restrict__ G,
                 float* __restrict__ O)
{
  __shared__ __align__(16) float stage[2][448]; // q[128] k[128] v[128] g[64]
  __shared__ float aS[64];
  const int tid = threadIdx.x;
  const int bh = (int)blockIdx.x;
  const int b = bh >> 3, h = bh & 7;

  const float* gptr = nullptr;
  int stride = 0;
  if (tid < 128)      { gptr = Q  + (size_t)(b * Tc) * Dc + h * KDc + tid;         stride = Dc; }
  else if (tid < 256) { gptr = Kt + (size_t)(b * Tc) * Dc + h * KDc + (tid - 128); stride = Dc; }
  else if (tid < 384) { gptr = V  + (size_t)(b * Tc) * Dc + h * KDc + (tid - 256); stride = Dc; }
  else if (tid < 448) { gptr = G  + (size_t)(b * Tc) * (Hc * Mc) + h * Mc + (tid - 384); stride = Hc * Mc; }

  float rA = (tid < 448) ? *gptr : 0.f;
  float hk[16], hv[16];
#pragma unroll
  for (int i = 0; i < 16; ++i) { hk[i] = 0.f; hv[i] = 0.f; }

  const int lane = tid & 63;
  const int m = tid >> 3, kg = tid & 7;
  const int vi = tid >> 2, mg = tid & 3;

  for (int t = 0; t < Tc; ++t) {
    float* st = stage[t & 1];
    if (tid < 448) st[tid] = rA;
    if (tid < 448 && t + 1 < Tc) rA = gptr[(size_t)(t + 1) * stride];
    __syncthreads(); // staging ready; aS from t-1 fully consumed
    const float* qS = st, *kS = st + 128, *vS = st + 256, *gS = st + 384;

    // every lane holds gate info for m=lane (used via shfl)
    float gel = __expf(gS[lane]);  // ge[m=lane]
    float sl  = 1.0f - gel;        // s[m] = 1 - exp(g[m])

    // phase 1: hk update + a[m] = q . hk[:,m]
    float gem = __shfl(gel, m, 64);
    float sm  = __shfl(sl, m, 64);
    float apart = 0.f;
    const float4* q4 = (const float4*)(qS + kg * 16);
    const float4* k4 = (const float4*)(kS + kg * 16);
#pragma unroll
    for (int j = 0; j < 4; ++j) {
      float4 qq = q4[j], kq = k4[j];
      hk[4 * j + 0] = fmaf(hk[4 * j + 0], gem, kq.x * sm); apart = fmaf(qq.x, hk[4 * j + 0], apart);
      hk[4 * j + 1] = fmaf(hk[4 * j + 1], gem, kq.y * sm); apart = fmaf(qq.y, hk[4 * j + 1], apart);
      hk[4 * j + 2] = fmaf(hk[4 * j + 2], gem, kq.z * sm); apart = fmaf(qq.z, hk[4 * j + 2], apart);
      hk[4 * j + 3] = fmaf(hk[4 * j + 3], gem, kq.w * sm); apart = fmaf(qq.w, hk[4 * j + 3], apart);
    }
    apart += __shfl_xor(apart, 1, 64);
    apart += __shfl_xor(apart, 2, 64);
    apart += __shfl_xor(apart, 4, 64);
    if (kg == 0) aS[m] = apart;
    __syncthreads();

    // phase 2: softmax over m, redundantly per-wave (lane <-> m)
    float av = aS[lane] * SCALE;
    float mx = av;
#pragma unroll
    for (int off = 32; off > 0; off >>= 1) mx = fmaxf(mx, __shfl_xor(mx, off, 64));
    float ev = __expf(av - mx);
    float es = ev;
#pragma unroll
    for (int off = 32; off > 0; off >>= 1) es += __shfl_xor(es, off, 64);
    float pl = ev / es; // p[m=lane]

    // phase 3: hv update + o[v] = sum_m p[m] hv[m,v]
    float vv = vS[vi];
    float opart = 0.f;
#pragma unroll
    for (int j = 0; j < 16; ++j) {
      int mm = mg * 16 + j;
      float gm2 = __shfl(gel, mm, 64);
      float sm2 = __shfl(sl, mm, 64);
      float pm  = __shfl(pl, mm, 64);
      hv[j] = fmaf(hv[j], gm2, sm2 * vv);
      opart = fmaf(pm, hv[j], opart);
    }
    opart += __shfl_xor(opart, 1, 64);
    opart += __shfl_xor(opart, 2, 64);
    if (mg == 0) O[(size_t)(b * Tc + t) * Dc + h * KDc + vi] = opart;
  }
}

// swish -> RMSNorm(g_weight); one block per row
__global__ __launch_bounds__(256)
void post_rms(const float* __restrict__ Oin, const float* __restrict__ gw,
              float* __restrict__ Nout)
{
  __shared__ float red[4];
  const int row = (int)blockIdx.x, tid = threadIdx.x;
  const float4 o4 = *(const float4*)(Oin + (size_t)row * Dc + tid * 4);
  float4 s4;
  s4.x = swishf(o4.x); s4.y = swishf(o4.y); s4.z = swishf(o4.z); s4.w = swishf(o4.w);
  float ss = s4.x * s4.x + s4.y * s4.y + s4.z * s4.z + s4.w * s4.w;
#pragma unroll
  for (int off = 32; off > 0; off >>= 1) ss += __shfl_xor(ss, off, 64);
  if ((tid & 63) == 0) red[tid >> 6] = ss;
  __syncthreads();
  float total = red[0] + red[1] + red[2] + red[3];
  float rms = rsqrtf(total * (1.0f / Dc) + 1e-5f);
  const float4 g4 = *(const float4*)(gw + tid * 4);
  float4 out;
  out.x = s4.x * rms * g4.x;
  out.y = s4.y * rms * g4.y;
  out.z = s4.z * rms * g4.z;
  out.w = s4.w * rms * g4.w;
  *(float4*)(Nout + (size_t)row * Dc + tid * 4) = out;
}

} // namespace

extern "C" void kernel_launch(void* const* d_in, const int* in_sizes, int n_in,
                              void* d_out, int out_size, void* d_ws, size_t ws_size,
                              hipStream_t stream)
{
  const float* x  = (const float*)d_in[0];
  const float* Wq = (const float*)d_in[1];
  const float* Wk = (const float*)d_in[2];
  const float* Wv = (const float*)d_in[3];
  const float* Wf = (const float*)d_in[4];
  const float* Wo = (const float*)d_in[5];
  const float* gw = (const float*)d_in[6];
  float* out = (float*)d_out;

  // workspace layout (bytes):
  //  qb 0..16M, kb 16M..32M, vb 32M..48M, gb 48M..56M, ob 56M..72M ; nb aliases qb
  char* ws = (char*)d_ws;
  float* qb = (float*)(ws);
  float* kb = (float*)(ws + (size_t)16777216);
  float* vb = (float*)(ws + (size_t)2 * 16777216);
  float* gb = (float*)(ws + (size_t)3 * 16777216);
  float* ob = (float*)(ws + (size_t)3 * 16777216 + 8388608);
  float* nb = qb; // q dead after scan

  dim3 blk(256);
  gemm_nt<1><<<dim3(16, 64), blk, 0, stream>>>(x, Wq, qb, ROWS, Dc, Dc);
  gemm_nt<1><<<dim3(16, 64), blk, 0, stream>>>(x, Wk, kb, ROWS, Dc, Dc);
  gemm_nt<1><<<dim3(16, 64), blk, 0, stream>>>(x, Wv, vb, ROWS, Dc, Dc);
  gemm_nt<2><<<dim3(8, 64),  blk, 0, stream>>>(x, Wf, gb, ROWS, Hc * Mc, Dc);
  scan_kernel<<<dim3(Bc * Hc), dim3(512), 0, stream>>>(qb, kb, vb, gb, ob);
  post_rms<<<dim3(ROWS), dim3(256), 0, stream>>>(ob, gw, nb);
  gemm_nt<0><<<dim3(16, 64), blk, 0, stream>>>(nb, Wo, out, ROWS, Dc, Dc);
}

// Round 10
// 398.868 us; speedup vs baseline: 12.8323x; 12.8323x over previous
//
#include <hip/hip_runtime.h>
#include <cstddef>
#include <cstdint>

namespace {

constexpr int Bc = 2, Tc = 2048, Dc = 1024, Hc = 8, Mc = 64, KDc = 128;
constexpr int ROWS = Bc * Tc; // 4096
constexpr int CH = 64, NC = Tc / CH; // chunk len, 32 chunks
constexpr float SCALE = 0.08838834764831845f; // 128^-0.5
constexpr float GATE_NORM_INV = 1.0f / 16.0f;

typedef __attribute__((ext_vector_type(8))) short bf16x8;
typedef __attribute__((ext_vector_type(4))) float f32x4;

__device__ __forceinline__ float swishf(float x) {
  return x / (1.0f + __expf(-x));
}
__device__ __forceinline__ float logsig16f(float x) {
  return (fminf(x, 0.f) - __logf(1.f + __expf(-fabsf(x)))) * GATE_NORM_INV;
}
__device__ __forceinline__ unsigned short f2bf(float f) {
  union { float f; unsigned u; } v; v.f = f;
  unsigned r = v.u + 0x7FFF + ((v.u >> 16) & 1); // RNE
  return (unsigned short)(r >> 16);
}
__device__ __forceinline__ void fma4(float a, const float4& b, float4& acc) {
  acc.x = fmaf(a, b.x, acc.x); acc.y = fmaf(a, b.y, acc.y);
  acc.z = fmaf(a, b.z, acc.z); acc.w = fmaf(a, b.w, acc.w);
}
__device__ __forceinline__ float dot4acc(const float4& a, const float4& b, float c) {
  c = fmaf(a.x, b.x, c); c = fmaf(a.y, b.y, c);
  c = fmaf(a.z, b.z, c); c = fmaf(a.w, b.w, c);
  return c;
}

// ---------------- MFMA GEMM: C = A @ Bw^T, A [M][1024] f32, Bw [N][1024] f32 ----------------
// Tile 128x128, 4 waves (2x2 of 64x64), BK=32, 16x16x32 bf16 MFMA, f32->bf16 cast in staging.
// EPI 0: plain f32 C0 (N=1024).  EPI 1: fused QKVF (N=3584): cols [0,1024) swish->C0,
// [1024,2048) swish->C1, [2048,3072) swish->C2, [3072,3584) logsig/16->C3 (width 512).
template<int EPI>
__global__ __launch_bounds__(256)
void gemm_mfma(const float* __restrict__ A,
               const float* __restrict__ B0, const float* __restrict__ B1,
               const float* __restrict__ B2, const float* __restrict__ B3,
               float* __restrict__ C0, float* __restrict__ C1,
               float* __restrict__ C2, float* __restrict__ C3)
{
  __shared__ __align__(16) unsigned short As[128 * 48]; // row stride 48 bf16 = 96B (16B-aligned)
  __shared__ __align__(16) unsigned short Bs[128 * 48];
  const int tid = threadIdx.x;
  const int bcol = (int)blockIdx.x, brow = (int)blockIdx.y;

  // block-uniform B source selection
  const float* Bw;
  {
    int n0 = bcol * 128;
    if (EPI == 0)       Bw = B0 + (size_t)n0 * 1024;
    else if (n0 < 1024) Bw = B0 + (size_t)n0 * 1024;
    else if (n0 < 2048) Bw = B1 + (size_t)(n0 - 1024) * 1024;
    else if (n0 < 3072) Bw = B2 + (size_t)(n0 - 2048) * 1024;
    else                Bw = B3 + (size_t)(n0 - 3072) * 1024;
  }

  // staging geometry: thread t handles row t>>1, 16 floats at col (t&1)*16
  const int ar = tid >> 1;
  const int ac = (tid & 1) << 4;
  const float* Ap = A + (size_t)(brow * 128 + ar) * 1024 + ac;
  const float* Bp = Bw + (size_t)ar * 1024 + ac;

  const int lane = tid & 63;
  const int w = tid >> 6, wr = w >> 1, wc = w & 1;
  const int lrow = lane & 15, lk = (lane >> 4) << 3;

  f32x4 acc[4][4];
#pragma unroll
  for (int i = 0; i < 4; ++i)
#pragma unroll
    for (int j = 0; j < 4; ++j)
#pragma unroll
      for (int r = 0; r < 4; ++r) acc[i][j][r] = 0.f;

  float4 a4[4], b4[4];
#pragma unroll
  for (int q = 0; q < 4; ++q) {
    a4[q] = *(const float4*)(Ap + q * 4);
    b4[q] = *(const float4*)(Bp + q * 4);
  }

  for (int k0 = 0; k0 < 1024; k0 += 32) {
    __syncthreads(); // previous compute done before overwriting LDS
#pragma unroll
    for (int q = 0; q < 4; ++q) {
      ushort4 ha, hb;
      ha.x = f2bf(a4[q].x); ha.y = f2bf(a4[q].y); ha.z = f2bf(a4[q].z); ha.w = f2bf(a4[q].w);
      hb.x = f2bf(b4[q].x); hb.y = f2bf(b4[q].y); hb.z = f2bf(b4[q].z); hb.w = f2bf(b4[q].w);
      *(ushort4*)&As[ar * 48 + ac + q * 4] = ha;
      *(ushort4*)&Bs[ar * 48 + ac + q * 4] = hb;
    }
    if (k0 + 32 < 1024) {
#pragma unroll
      for (int q = 0; q < 4; ++q) {
        a4[q] = *(const float4*)(Ap + k0 + 32 + q * 4);
        b4[q] = *(const float4*)(Bp + k0 + 32 + q * 4);
      }
    }
    __syncthreads();

    bf16x8 av[4], bv[4];
#pragma unroll
    for (int i = 0; i < 4; ++i)
      av[i] = *(const bf16x8*)&As[(wr * 64 + i * 16 + lrow) * 48 + lk];
#pragma unroll
    for (int j = 0; j < 4; ++j)
      bv[j] = *(const bf16x8*)&Bs[(wc * 64 + j * 16 + lrow) * 48 + lk];
#pragma unroll
    for (int i = 0; i < 4; ++i)
#pragma unroll
      for (int j = 0; j < 4; ++j)
        acc[i][j] = __builtin_amdgcn_mfma_f32_16x16x32_bf16(av[i], bv[j], acc[i][j], 0, 0, 0);
  }

  // epilogue: D row = (lane>>4)*4 + reg, col = lane&15  [m89-verified]
#pragma unroll
  for (int i = 0; i < 4; ++i) {
#pragma unroll
    for (int j = 0; j < 4; ++j) {
#pragma unroll
      for (int r = 0; r < 4; ++r) {
        int row = brow * 128 + wr * 64 + i * 16 + ((lane >> 4) << 2) + r;
        int n   = bcol * 128 + wc * 64 + j * 16 + (lane & 15);
        float v = acc[i][j][r];
        if (EPI == 0) {
          C0[(size_t)row * 1024 + n] = v;
        } else {
          if (n < 1024)      C0[(size_t)row * 1024 + n]          = swishf(v);
          else if (n < 2048) C1[(size_t)row * 1024 + (n - 1024)] = swishf(v);
          else if (n < 3072) C2[(size_t)row * 1024 + (n - 2048)] = swishf(v);
          else               C3[(size_t)row * 512  + (n - 3072)] = logsig16f(v);
        }
      }
    }
  }
}

// ---------------- Phase 1: per-chunk local state deltas ----------------
// grid (NC, 16) blocks of 256.  St[bh][c][ dHk(128x64) | dHv(64x128) ], Gc[bh][c][m]=e^{GammaC}
__global__ __launch_bounds__(256)
void scan_phase1(const float* __restrict__ K_, const float* __restrict__ V_,
                 const float* __restrict__ G_, float* __restrict__ St,
                 float* __restrict__ Gc)
{
  __shared__ __align__(16) float uls[CH][68];   // g, then u'[tau][m] = s*e^{-Gamma}
  __shared__ __align__(16) float Bb[CH][132];   // K then V chunk
  __shared__ float egcs[CH];
  const int tid = threadIdx.x;
  const int c = (int)blockIdx.x, bh = (int)blockIdx.y;
  const int b = bh >> 3, h = bh & 7;
  const int t0 = c * CH;

  { // load g chunk [64][64]
    const int gr = tid >> 2, gc0 = (tid & 3) << 4;
    const float* gsrc = G_ + (size_t)(b * Tc + t0 + gr) * (Hc * Mc) + h * Mc + gc0;
#pragma unroll
    for (int j = 0; j < 4; ++j)
      *(float4*)&uls[gr][gc0 + 4 * j] = *(const float4*)(gsrc + 4 * j);
  }
  { // load K chunk [64][128]
    const float* ksrc = K_ + (size_t)(b * Tc + t0) * Dc + h * KDc;
#pragma unroll
    for (int j = 0; j < 8; ++j) {
      int fi = tid + j * 256;
      int r = fi >> 5, cc = (fi & 31) << 2;
      *(float4*)&Bb[r][cc] = *(const float4*)(ksrc + (size_t)r * Dc + cc);
    }
  }
  __syncthreads();
  if (tid < CH) { // column cumsum -> u', e^{GammaC}
    float run = 0.f;
    for (int t = 0; t < CH; ++t) {
      float gv = uls[t][tid];
      run += gv;
      uls[t][tid] = (1.0f - __expf(gv)) * __expf(-run);
    }
    float eg = __expf(run);
    egcs[tid] = eg;
    Gc[((size_t)bh * NC + c) * CH + tid] = eg;
  }
  __syncthreads();
  const size_t stbase = ((size_t)bh * NC + c) * 16384;
  { // dHk[k][m] = egc[m] * sum_tau K[tau][k] u'[tau][m]
    const int k0 = (tid >> 3) << 2, m0 = (tid & 7) << 3;
    float4 acc[4][2];
#pragma unroll
    for (int i = 0; i < 4; ++i) { acc[i][0] = make_float4(0,0,0,0); acc[i][1] = make_float4(0,0,0,0); }
    for (int tau = 0; tau < CH; ++tau) {
      float4 kv = *(const float4*)&Bb[tau][k0];
      float4 u0 = *(const float4*)&uls[tau][m0];
      float4 u1 = *(const float4*)&uls[tau][m0 + 4];
      fma4(kv.x, u0, acc[0][0]); fma4(kv.x, u1, acc[0][1]);
      fma4(kv.y, u0, acc[1][0]); fma4(kv.y, u1, acc[1][1]);
      fma4(kv.z, u0, acc[2][0]); fma4(kv.z, u1, acc[2][1]);
      fma4(kv.w, u0, acc[3][0]); fma4(kv.w, u1, acc[3][1]);
    }
    float4 e0 = *(const float4*)&egcs[m0];
    float4 e1 = *(const float4*)&egcs[m0 + 4];
#pragma unroll
    for (int i = 0; i < 4; ++i) {
      float4 o0, o1;
      o0.x = acc[i][0].x * e0.x; o0.y = acc[i][0].y * e0.y; o0.z = acc[i][0].z * e0.z; o0.w = acc[i][0].w * e0.w;
      o1.x = acc[i][1].x * e1.x; o1.y = acc[i][1].y * e1.y; o1.z = acc[i][1].z * e1.z; o1.w = acc[i][1].w * e1.w;
      float* dst = St + stbase + (size_t)(k0 + i) * 64 + m0;
      *(float4*)dst = o0; *(float4*)(dst + 4) = o1;
    }
  }
  __syncthreads();
  { // load V chunk over K
    const float* vsrc = V_ + (size_t)(b * Tc + t0) * Dc + h * KDc;
#pragma unroll
    for (int j = 0; j < 8; ++j) {
      int fi = tid + j * 256;
      int r = fi >> 5, cc = (fi & 31) << 2;
      *(float4*)&Bb[r][cc] = *(const float4*)(vsrc + (size_t)r * Dc + cc);
    }
  }
  __syncthreads();
  { // dHv[m][v] = egc[m] * sum_tau u'[tau][m] V[tau][v]
    const int m0 = (tid >> 4) << 2, v0 = (tid & 15) << 3;
    float4 acc[4][2];
#pragma unroll
    for (int i = 0; i < 4; ++i) { acc[i][0] = make_float4(0,0,0,0); acc[i][1] = make_float4(0,0,0,0); }
    for (int tau = 0; tau < CH; ++tau) {
      float4 u4 = *(const float4*)&uls[tau][m0];
      float4 va = *(const float4*)&Bb[tau][v0];
      float4 vb = *(const float4*)&Bb[tau][v0 + 4];
      fma4(u4.x, va, acc[0][0]); fma4(u4.x, vb, acc[0][1]);
      fma4(u4.y, va, acc[1][0]); fma4(u4.y, vb, acc[1][1]);
      fma4(u4.z, va, acc[2][0]); fma4(u4.z, vb, acc[2][1]);
      fma4(u4.w, va, acc[3][0]); fma4(u4.w, vb, acc[3][1]);
    }
#pragma unroll
    for (int i = 0; i < 4; ++i) {
      float eg = egcs[m0 + i];
      float4 o0 = acc[i][0], o1 = acc[i][1];
      o0.x *= eg; o0.y *= eg; o0.z *= eg; o0.w *= eg;
      o1.x *= eg; o1.y *= eg; o1.z *= eg; o1.w *= eg;
      float* dst = St + stbase + 8192 + (size_t)(m0 + i) * 128 + v0;
      *(float4*)dst = o0; *(float4*)(dst + 4) = o1;
    }
  }
}

// ---------------- Phase 2: inter-chunk state scan (in place) ----------------
__global__ __launch_bounds__(256)
void scan_phase2(float* St, const float* __restrict__ Gc)
{
  const int tid = threadIdx.x;
  const int bh = (int)blockIdx.x, slice = (int)blockIdx.y;
  const int e0 = slice * 1024 + tid * 4;
  const bool isHk = e0 < 8192;
  float* base = St + (size_t)bh * NC * 16384 + e0;
  const float* gcp = Gc + (size_t)bh * NC * CH;
  float4 run = make_float4(0, 0, 0, 0);
  float4 d = *(float4*)base;
  for (int c = 0; c < NC; ++c) {
    float4 dn = make_float4(0, 0, 0, 0);
    if (c + 1 < NC) dn = *(float4*)(base + (size_t)(c + 1) * 16384);
    float4 ge;
    if (isHk) {
      ge = *(const float4*)(gcp + c * CH + (e0 & 63));
    } else {
      float g1 = gcp[c * CH + ((e0 - 8192) >> 7)];
      ge = make_float4(g1, g1, g1, g1);
    }
    *(float4*)(base + (size_t)c * 16384) = run;
    run.x = fmaf(run.x, ge.x, d.x);
    run.y = fmaf(run.y, ge.y, d.y);
    run.z = fmaf(run.z, ge.z, d.z);
    run.w = fmaf(run.w, ge.w, d.w);
    d = dn;
  }
}

// ---------------- Phase 3: per-chunk outputs ----------------
__global__ __launch_bounds__(256)
void scan_phase3(const float* __restrict__ Q_, const float* __restrict__ K_,
                 const float* __restrict__ V_, const float* __restrict__ G_,
                 const float* __restrict__ St, float* __restrict__ O_)
{
  __shared__ __align__(16) float Qs[CH][132];
  __shared__ __align__(16) float Bf[8704];      // K[64][132] -> Hk0[128][68] -> V[64][132] -> Hv0[64][132]
  __shared__ __align__(16) float us[CH][68];    // u'[tau][m]
  __shared__ __align__(16) float es[CH][68];    // raw g -> e^{Gamma_t[m]}
  __shared__ __align__(16) float Ss[CH][68];    // S masked -> W
  __shared__ __align__(16) float Ps[CH][68];    // A -> P2

  const int tid = threadIdx.x;
  const int c = (int)blockIdx.x, bh = (int)blockIdx.y;
  const int b = bh >> 3, h = bh & 7;
  const int t0 = c * CH;
  const size_t stbase = ((size_t)bh * NC + c) * 16384;

  // 1. load g -> es(raw), Q -> Qs, K -> Bf
  {
    const int gr = tid >> 2, gc0 = (tid & 3) << 4;
    const float* gsrc = G_ + (size_t)(b * Tc + t0 + gr) * (Hc * Mc) + h * Mc + gc0;
#pragma unroll
    for (int j = 0; j < 4; ++j)
      *(float4*)&es[gr][gc0 + 4 * j] = *(const float4*)(gsrc + 4 * j);
    const float* qsrc = Q_ + (size_t)(b * Tc + t0) * Dc + h * KDc;
    const float* ksrc = K_ + (size_t)(b * Tc + t0) * Dc + h * KDc;
#pragma unroll
    for (int j = 0; j < 8; ++j) {
      int fi = tid + j * 256;
      int r = fi >> 5, cc4 = (fi & 31) << 2;
      *(float4*)&Qs[r][cc4] = *(const float4*)(qsrc + (size_t)r * Dc + cc4);
      *(float4*)&Bf[r * 132 + cc4] = *(const float4*)(ksrc + (size_t)r * Dc + cc4);
    }
  }
  __syncthreads();
  // 2a. cumsum (wave 0) -> us, es
  if (tid < CH) {
    float run = 0.f;
    for (int t = 0; t < CH; ++t) {
      float gv = es[t][tid];
      run += gv;
      us[t][tid] = (1.0f - __expf(gv)) * __expf(-run);
      es[t][tid] = __expf(run);
    }
  }
  // 2b. S = Q K^T, causal-masked (incl. diagonal)
  const int tt = tid >> 4, ccg = tid & 15;
  {
    const int tr = tt << 2, tc = ccg << 2;
    float4 acc[4];
#pragma unroll
    for (int i = 0; i < 4; ++i) acc[i] = make_float4(0, 0, 0, 0);
    for (int k = 0; k < KDc; k += 4) {
      float4 kr0 = *(const float4*)&Bf[(tc + 0) * 132 + k];
      float4 kr1 = *(const float4*)&Bf[(tc + 1) * 132 + k];
      float4 kr2 = *(const float4*)&Bf[(tc + 2) * 132 + k];
      float4 kr3 = *(const float4*)&Bf[(tc + 3) * 132 + k];
#pragma unroll
      for (int i = 0; i < 4; ++i) {
        float4 qi = *(const float4*)&Qs[tr + i][k];
        acc[i].x = dot4acc(qi, kr0, acc[i].x);
        acc[i].y = dot4acc(qi, kr1, acc[i].y);
        acc[i].z = dot4acc(qi, kr2, acc[i].z);
        acc[i].w = dot4acc(qi, kr3, acc[i].w);
      }
    }
#pragma unroll
    for (int i = 0; i < 4; ++i) {
      float4 w;
      w.x = (tc + 0 <= tr + i) ? acc[i].x : 0.f;
      w.y = (tc + 1 <= tr + i) ? acc[i].y : 0.f;
      w.z = (tc + 2 <= tr + i) ? acc[i].z : 0.f;
      w.w = (tc + 3 <= tr + i) ? acc[i].w : 0.f;
      *(float4*)&Ss[tr + i][tc] = w;
    }
  }
  __syncthreads();
  // 3. Hk0 -> Bf as [128][68]
  {
#pragma unroll
    for (int j = 0; j < 8; ++j) {
      int fi = tid + j * 256;
      int k = fi >> 4, m4 = (fi & 15) << 2;
      *(float4*)&Bf[k * 68 + m4] = *(const float4*)(St + stbase + (size_t)k * 64 + m4);
    }
  }
  __syncthreads();
  // 4. A[t][m] = SCALE * e^{Gamma} * (Q@Hk0 + S@u') -> Ps
  {
    const int tr = tt << 2, m0 = ccg << 2;
    float4 acc[4];
#pragma unroll
    for (int i = 0; i < 4; ++i) acc[i] = make_float4(0, 0, 0, 0);
    for (int tau = 0; tau < CH; tau += 4) {
      float4 u0 = *(const float4*)&us[tau + 0][m0];
      float4 u1 = *(const float4*)&us[tau + 1][m0];
      float4 u2 = *(const float4*)&us[tau + 2][m0];
      float4 u3 = *(const float4*)&us[tau + 3][m0];
#pragma unroll
      for (int i = 0; i < 4; ++i) {
        float4 s4 = *(const float4*)&Ss[tr + i][tau];
        fma4(s4.x, u0, acc[i]); fma4(s4.y, u1, acc[i]);
        fma4(s4.z, u2, acc[i]); fma4(s4.w, u3, acc[i]);
      }
    }
    for (int k = 0; k < KDc; k += 4) {
      float4 h0 = *(const float4*)&Bf[(k + 0) * 68 + m0];
      float4 h1 = *(const float4*)&Bf[(k + 1) * 68 + m0];
      float4 h2 = *(const float4*)&Bf[(k + 2) * 68 + m0];
      float4 h3 = *(const float4*)&Bf[(k + 3) * 68 + m0];
#pragma unroll
      for (int i = 0; i < 4; ++i) {
        float4 q4 = *(const float4*)&Qs[tr + i][k];
        fma4(q4.x, h0, acc[i]); fma4(q4.y, h1, acc[i]);
        fma4(q4.z, h2, acc[i]); fma4(q4.w, h3, acc[i]);
      }
    }
#pragma unroll
    for (int i = 0; i < 4; ++i) {
      float4 ev = *(const float4*)&es[tr + i][m0];
      float4 ov;
      ov.x = SCALE * ev.x * acc[i].x;
      ov.y = SCALE * ev.y * acc[i].y;
      ov.z = SCALE * ev.z * acc[i].z;
      ov.w = SCALE * ev.w * acc[i].w;
      *(float4*)&Ps[tr + i][m0] = ov;
    }
  }
  __syncthreads();
  // 5. row softmax over m; w = p * e^{Gamma} -> Ss
  {
    const int row = tid >> 2, m0 = (tid & 3) << 4;
    float4 a0 = *(const float4*)&Ps[row][m0];
    float4 a1 = *(const float4*)&Ps[row][m0 + 4];
    float4 a2 = *(const float4*)&Ps[row][m0 + 8];
    float4 a3 = *(const float4*)&Ps[row][m0 + 12];
    float mx = fmaxf(fmaxf(fmaxf(a0.x, a0.y), fmaxf(a0.z, a0.w)),
                     fmaxf(fmaxf(a1.x, a1.y), fmaxf(a1.z, a1.w)));
    mx = fmaxf(mx, fmaxf(fmaxf(fmaxf(a2.x, a2.y), fmaxf(a2.z, a2.w)),
                         fmaxf(fmaxf(a3.x, a3.y), fmaxf(a3.z, a3.w))));
    mx = fmaxf(mx, __shfl_xor(mx, 1, 64));
    mx = fmaxf(mx, __shfl_xor(mx, 2, 64));
    a0.x = __expf(a0.x - mx); a0.y = __expf(a0.y - mx); a0.z = __expf(a0.z - mx); a0.w = __expf(a0.w - mx);
    a1.x = __expf(a1.x - mx); a1.y = __expf(a1.y - mx); a1.z = __expf(a1.z - mx); a1.w = __expf(a1.w - mx);
    a2.x = __expf(a2.x - mx); a2.y = __expf(a2.y - mx); a2.z = __expf(a2.z - mx); a2.w = __expf(a2.w - mx);
    a3.x = __expf(a3.x - mx); a3.y = __expf(a3.y - mx); a3.z = __expf(a3.z - mx); a3.w = __expf(a3.w - mx);
    float sm = a0.x + a0.y + a0.z + a0.w + a1.x + a1.y + a1.z + a1.w
             + a2.x + a2.y + a2.z + a2.w + a3.x + a3.y + a3.z + a3.w;
    sm += __shfl_xor(sm, 1, 64);
    sm += __shfl_xor(sm, 2, 64);
    float inv = 1.0f / sm;
    float4 e0 = *(const float4*)&es[row][m0];
    float4 e1 = *(const float4*)&es[row][m0 + 4];
    float4 e2 = *(const float4*)&es[row][m0 + 8];
    float4 e3 = *(const float4*)&es[row][m0 + 12];
    a0.x *= inv * e0.x; a0.y *= inv * e0.y; a0.z *= inv * e0.z; a0.w *= inv * e0.w;
    a1.x *= inv * e1.x; a1.y *= inv * e1.y; a1.z *= inv * e1.z; a1.w *= inv * e1.w;
    a2.x *= inv * e2.x; a2.y *= inv * e2.y; a2.z *= inv * e2.z; a2.w *= inv * e2.w;
    a3.x *= inv * e3.x; a3.y *= inv * e3.y; a3.z *= inv * e3.z; a3.w *= inv * e3.w;
    *(float4*)&Ss[row][m0] = a0;
    *(float4*)&Ss[row][m0 + 4] = a1;
    *(float4*)&Ss[row][m0 + 8] = a2;
    *(float4*)&Ss[row][m0 + 12] = a3;
  }
  // 6. load V -> Bf (Hk0 dead)
  {
    const float* vsrc = V_ + (size_t)(b * Tc + t0) * Dc + h * KDc;
#pragma unroll
    for (int j = 0; j < 8; ++j) {
      int fi = tid + j * 256;
      int r = fi >> 5, cc4 = (fi & 31) << 2;
      *(float4*)&Bf[r * 132 + cc4] = *(const float4*)(vsrc + (size_t)r * Dc + cc4);
    }
  }
  __syncthreads();
  // 7. P2[t][tau] = sum_m W[t][m] u'[tau][m], masked -> Ps
  {
    const int tr = tt << 2, tc = ccg << 2;
    float4 acc[4];
#pragma unroll
    for (int i = 0; i < 4; ++i) acc[i] = make_float4(0, 0, 0, 0);
    for (int m = 0; m < CH; m += 4) {
      float4 u0 = *(const float4*)&us[tc + 0][m];
      float4 u1 = *(const float4*)&us[tc + 1][m];
      float4 u2 = *(const float4*)&us[tc + 2][m];
      float4 u3 = *(const float4*)&us[tc + 3][m];
#pragma unroll
      for (int i = 0; i < 4; ++i) {
        float4 w4 = *(const float4*)&Ss[tr + i][m];
        acc[i].x = dot4acc(w4, u0, acc[i].x);
        acc[i].y = dot4acc(w4, u1, acc[i].y);
        acc[i].z = dot4acc(w4, u2, acc[i].z);
        acc[i].w = dot4acc(w4, u3, acc[i].w);
      }
    }
#pragma unroll
    for (int i = 0; i < 4; ++i) {
      float4 w;
      w.x = (tc + 0 <= tr + i) ? acc[i].x : 0.f;
      w.y = (tc + 1 <= tr + i) ? acc[i].y : 0.f;
      w.z = (tc + 2 <= tr + i) ? acc[i].z : 0.f;
      w.w = (tc + 3 <= tr + i) ? acc[i].w : 0.f;
      *(float4*)&Ps[tr + i][tc] = w;
    }
  }
  __syncthreads();
  // 8. O = P2 @ V  (accumulate in regs)
  const int tr = tt << 2, v0 = ccg << 3;
  float4 accO[4][2];
#pragma unroll
  for (int i = 0; i < 4; ++i) { accO[i][0] = make_float4(0,0,0,0); accO[i][1] = make_float4(0,0,0,0); }
  for (int tau = 0; tau < CH; tau += 4) {
    float4 pr[4];
#pragma unroll
    for (int i = 0; i < 4; ++i) pr[i] = *(const float4*)&Ps[tr + i][tau];
#pragma unroll
    for (int d = 0; d < 4; ++d) {
      float4 va = *(const float4*)&Bf[(tau + d) * 132 + v0];
      float4 vb = *(const float4*)&Bf[(tau + d) * 132 + v0 + 4];
#pragma unroll
      for (int i = 0; i < 4; ++i) {
        float p = (d == 0) ? pr[i].x : (d == 1) ? pr[i].y : (d == 2) ? pr[i].z : pr[i].w;
        fma4(p, va, accO[i][0]); fma4(p, vb, accO[i][1]);
      }
    }
  }
  __syncthreads();
  // 9. Hv0 -> Bf
  {
#pragma unroll
    for (int j = 0; j < 8; ++j) {
      int fi = tid + j * 256;
      int m = fi >> 5, c4 = (fi & 31) << 2;
      *(float4*)&Bf[m * 132 + c4] = *(const float4*)(St + stbase + 8192 + (size_t)m * 128 + c4);
    }
  }
  __syncthreads();
  // 10. O += W @ Hv0 ; store
  for (int m = 0; m < CH; m += 4) {
    float4 wr[4];
#pragma unroll
    for (int i = 0; i < 4; ++i) wr[i] = *(const float4*)&Ss[tr + i][m];
#pragma unroll
    for (int d = 0; d < 4; ++d) {
      float4 ha = *(const float4*)&Bf[(m + d) * 132 + v0];
      float4 hb = *(const float4*)&Bf[(m + d) * 132 + v0 + 4];
#pragma unroll
      for (int i = 0; i < 4; ++i) {
        float w = (d == 0) ? wr[i].x : (d == 1) ? wr[i].y : (d == 2) ? wr[i].z : wr[i].w;
        fma4(w, ha, accO[i][0]); fma4(w, hb, accO[i][1]);
      }
    }
  }
#pragma unroll
  for (int i = 0; i < 4; ++i) {
    float* dst = O_ + (size_t)(b * Tc + t0 + tr + i) * Dc + h * KDc + v0;
    *(float4*)dst = accO[i][0];
    *(float4*)(dst + 4) = accO[i][1];
  }
}

// ---------------- post: swish -> RMSNorm ----------------
__global__ __launch_bounds__(256)
void post_rms(const float* __restrict__ Oin, const float* __restrict__ gw,
              float* __restrict__ Nout)
{
  __shared__ float red[4];
  const int row = (int)blockIdx.x, tid = threadIdx.x;
  const float4 o4 = *(const float4*)(Oin + (size_t)row * Dc + tid * 4);
  float4 s4;
  s4.x = swishf(o4.x); s4.y = swishf(o4.y); s4.z = swishf(o4.z); s4.w = swishf(o4.w);
  float ss = s4.x * s4.x + s4.y * s4.y + s4.z * s4.z + s4.w * s4.w;
#pragma unroll
  for (int off = 32; off > 0; off >>= 1) ss += __shfl_xor(ss, off, 64);
  if ((tid & 63) == 0) red[tid >> 6] = ss;
  __syncthreads();
  float total = red[0] + red[1] + red[2] + red[3];
  float rms = rsqrtf(total * (1.0f / Dc) + 1e-5f);
  const float4 g4 = *(const float4*)(gw + tid * 4);
  float4 out;
  out.x = s4.x * rms * g4.x;
  out.y = s4.y * rms * g4.y;
  out.z = s4.z * rms * g4.z;
  out.w = s4.w * rms * g4.w;
  *(float4*)(Nout + (size_t)row * Dc + tid * 4) = out;
}

} // namespace

extern "C" void kernel_launch(void* const* d_in, const int* in_sizes, int n_in,
                              void* d_out, int out_size, void* d_ws, size_t ws_size,
                              hipStream_t stream)
{
  const float* x  = (const float*)d_in[0];
  const float* Wq = (const float*)d_in[1];
  const float* Wk = (const float*)d_in[2];
  const float* Wv = (const float*)d_in[3];
  const float* Wf = (const float*)d_in[4];
  const float* Wo = (const float*)d_in[5];
  const float* gw = (const float*)d_in[6];
  float* out = (float*)d_out;

  // workspace layout (MB offsets): qb 0, kb 16, vb 32, gb 48 (8), st 56 (32), gcb 88, ob 89 (16)
  char* ws = (char*)d_ws;
  const size_t MB = 1ull << 20;
  float* qb  = (float*)(ws);
  float* kb  = (float*)(ws + 16 * MB);
  float* vb  = (float*)(ws + 32 * MB);
  float* gb  = (float*)(ws + 48 * MB);
  float* st  = (float*)(ws + 56 * MB);
  float* gcb = (float*)(ws + 88 * MB);
  float* ob  = (float*)(ws + 89 * MB);
  float* nb  = qb; // q dead after phase 3

  dim3 blk(256);
  // fused QKVF projection GEMM: N = 3*1024 + 512 = 3584
  gemm_mfma<1><<<dim3(28, 32), blk, 0, stream>>>(x, Wq, Wk, Wv, Wf, qb, kb, vb, gb);
  scan_phase1<<<dim3(NC, 16), blk, 0, stream>>>(kb, vb, gb, st, gcb);
  scan_phase2<<<dim3(16, 16), blk, 0, stream>>>(st, gcb);
  scan_phase3<<<dim3(NC, 16), blk, 0, stream>>>(qb, kb, vb, gb, st, ob);
  post_rms<<<dim3(ROWS), blk, 0, stream>>>(ob, gw, nb);
  gemm_mfma<0><<<dim3(8, 32), blk, 0, stream>>>(nb, Wo, nullptr, nullptr, nullptr,
                                                out, nullptr, nullptr, nullptr);
}

// Round 11
// 318.190 us; speedup vs baseline: 16.0859x; 1.2536x over previous
//
#include <hip/hip_runtime.h>
#include <cstddef>
#include <cstdint>

namespace {

constexpr int Bc = 2, Tc = 2048, Dc = 1024, Hc = 8, Mc = 64, KDc = 128;
constexpr int ROWS = Bc * Tc; // 4096
constexpr int CH = 64, NC = Tc / CH; // chunk len, 32 chunks
constexpr float SCALE = 0.08838834764831845f; // 128^-0.5
constexpr float GATE_NORM_INV = 1.0f / 16.0f;

typedef __attribute__((ext_vector_type(8))) short bf16x8;
typedef __attribute__((ext_vector_type(4))) float f32x4;

__device__ __forceinline__ float swishf(float x) {
  return x / (1.0f + __expf(-x));
}
__device__ __forceinline__ float logsig16f(float x) {
  return (fminf(x, 0.f) - __logf(1.f + __expf(-fabsf(x)))) * GATE_NORM_INV;
}
__device__ __forceinline__ unsigned short f2bf(float f) {
  union { float f; unsigned u; } v; v.f = f;
  unsigned r = v.u + 0x7FFF + ((v.u >> 16) & 1); // RNE
  return (unsigned short)(r >> 16);
}
__device__ __forceinline__ void fma4(float a, const float4& b, float4& acc) {
  acc.x = fmaf(a, b.x, acc.x); acc.y = fmaf(a, b.y, acc.y);
  acc.z = fmaf(a, b.z, acc.z); acc.w = fmaf(a, b.w, acc.w);
}
__device__ __forceinline__ float dot4acc(const float4& a, const float4& b, float c) {
  c = fmaf(a.x, b.x, c); c = fmaf(a.y, b.y, c);
  c = fmaf(a.z, b.z, c); c = fmaf(a.w, b.w, c);
  return c;
}

#define GLOAD_LDS16(g, l) __builtin_amdgcn_global_load_lds( \
    (const __attribute__((address_space(1))) unsigned int*)(g), \
    (__attribute__((address_space(3))) unsigned int*)(l), 16, 0, 0)

// ---------------- one-shot f32 -> bf16 conversion (x, Wq|Wk|Wv|Wf concat, Wo) ----------------
// segments (elems): x 4194304 | wq 1048576 | wk 1048576 | wv 1048576 | wf 524288 | wo 1048576
// total 8912896 = 4352 blocks * 256 threads * 8 elems
__global__ __launch_bounds__(256)
void cvt_bf16_all(const float* __restrict__ x, const float* __restrict__ wq,
                  const float* __restrict__ wk, const float* __restrict__ wv,
                  const float* __restrict__ wf, const float* __restrict__ wo,
                  unsigned short* __restrict__ xb, unsigned short* __restrict__ wqkvf,
                  unsigned short* __restrict__ wob)
{
  long e = ((long)blockIdx.x * 256 + threadIdx.x) * 8;
  const float* src; unsigned short* dst; long off;
  if (e < 4194304L)      { src = x;  dst = xb;              off = e; }
  else if (e < 5242880L) { src = wq; dst = wqkvf;           off = e - 4194304L; }
  else if (e < 6291456L) { src = wk; dst = wqkvf + 1048576; off = e - 5242880L; }
  else if (e < 7340032L) { src = wv; dst = wqkvf + 2097152; off = e - 6291456L; }
  else if (e < 7864320L) { src = wf; dst = wqkvf + 3145728; off = e - 7340032L; }
  else                   { src = wo; dst = wob;             off = e - 7864320L; }
  float4 a = *(const float4*)(src + off);
  float4 b = *(const float4*)(src + off + 4);
  ushort4 h0, h1;
  h0.x = f2bf(a.x); h0.y = f2bf(a.y); h0.z = f2bf(a.z); h0.w = f2bf(a.w);
  h1.x = f2bf(b.x); h1.y = f2bf(b.y); h1.z = f2bf(b.z); h1.w = f2bf(b.w);
  *(ushort4*)(dst + off) = h0;
  *(ushort4*)(dst + off + 4) = h1;
}

// ---------------- bf16 MFMA GEMM: C = A @ B^T, A [M][1024], B [N][1024] bf16 row-major ------
// 128x128 tile, 4 waves (2x2 of 64x64), BK=32, global_load_lds width-16 staging (linear LDS).
// EPI 0: plain f32 C0 (N=1024). EPI 1: N=3584 concat: [0,1024) swish->C0, [1024,2048) swish->C1,
// [2048,3072) swish->C2, [3072,3584) logsig/16->C3 (width 512).
template<int EPI>
__global__ __launch_bounds__(256)
void gemm_bt(const unsigned short* __restrict__ A, const unsigned short* __restrict__ Bm,
             float* __restrict__ C0, float* __restrict__ C1,
             float* __restrict__ C2, float* __restrict__ C3)
{
  __shared__ __align__(16) unsigned short As[128 * 32]; // rows contiguous, 64B/row
  __shared__ __align__(16) unsigned short Bs[128 * 32];
  const int tid = threadIdx.x;
  const int lane = tid & 63, w = tid >> 6;
  const int bcol = (int)blockIdx.x, brow = (int)blockIdx.y;
  const int wr = w >> 1, wc = w & 1;
  const int lrow = lane & 15, lk8 = (lane >> 4) << 3;

  // staging: wave w covers rows w*32..w*32+31 (2 instrs of 16 rows); lane l -> row +l/4, col (l&3)*8
  const int srow = w * 32 + (lane >> 2);
  const int scol = (lane & 3) << 3;
  const unsigned short* Ag0 = A + (size_t)(brow * 128 + srow) * 1024 + scol;
  const unsigned short* Ag1 = Ag0 + (size_t)16 * 1024;
  const unsigned short* Bg0 = Bm + (size_t)(bcol * 128 + srow) * 1024 + scol;
  const unsigned short* Bg1 = Bg0 + (size_t)16 * 1024;
  unsigned short* Al0 = As + w * 1024;        // byte w*2048
  unsigned short* Al1 = As + w * 1024 + 512;  // +1024B
  unsigned short* Bl0 = Bs + w * 1024;
  unsigned short* Bl1 = Bs + w * 1024 + 512;

  f32x4 acc[4][4];
#pragma unroll
  for (int i = 0; i < 4; ++i)
#pragma unroll
    for (int j = 0; j < 4; ++j)
#pragma unroll
      for (int r = 0; r < 4; ++r) acc[i][j][r] = 0.f;

  for (int k0 = 0; k0 < 1024; k0 += 32) {
    __syncthreads(); // previous iteration's LDS reads complete
    GLOAD_LDS16(Ag0 + k0, Al0);
    GLOAD_LDS16(Ag1 + k0, Al1);
    GLOAD_LDS16(Bg0 + k0, Bl0);
    GLOAD_LDS16(Bg1 + k0, Bl1);
    __syncthreads(); // vmcnt(0) drain before barrier -> staged data visible

    bf16x8 av[4], bv[4];
#pragma unroll
    for (int i = 0; i < 4; ++i)
      av[i] = *(const bf16x8*)&As[(wr * 64 + i * 16 + lrow) * 32 + lk8];
#pragma unroll
    for (int j = 0; j < 4; ++j)
      bv[j] = *(const bf16x8*)&Bs[(wc * 64 + j * 16 + lrow) * 32 + lk8];
#pragma unroll
    for (int i = 0; i < 4; ++i)
#pragma unroll
      for (int j = 0; j < 4; ++j)
        acc[i][j] = __builtin_amdgcn_mfma_f32_16x16x32_bf16(av[i], bv[j], acc[i][j], 0, 0, 0);
  }

  // epilogue: D row = (lane>>4)*4 + r, col = lane&15  [HW-validated round 10]
#pragma unroll
  for (int i = 0; i < 4; ++i) {
#pragma unroll
    for (int j = 0; j < 4; ++j) {
#pragma unroll
      for (int r = 0; r < 4; ++r) {
        int row = brow * 128 + wr * 64 + i * 16 + ((lane >> 4) << 2) + r;
        int n   = bcol * 128 + wc * 64 + j * 16 + (lane & 15);
        float v = acc[i][j][r];
        if (EPI == 0) {
          C0[(size_t)row * 1024 + n] = v;
        } else {
          if (n < 1024)      C0[(size_t)row * 1024 + n]          = swishf(v);
          else if (n < 2048) C1[(size_t)row * 1024 + (n - 1024)] = swishf(v);
          else if (n < 3072) C2[(size_t)row * 1024 + (n - 2048)] = swishf(v);
          else               C3[(size_t)row * 512  + (n - 3072)] = logsig16f(v);
        }
      }
    }
  }
}

// ---------------- Phase 1: per-chunk local state deltas ----------------
__global__ __launch_bounds__(256)
void scan_phase1(const float* __restrict__ K_, const float* __restrict__ V_,
                 const float* __restrict__ G_, float* __restrict__ St,
                 float* __restrict__ Gc)
{
  __shared__ __align__(16) float uls[CH][68];   // g, then u'[tau][m] = s*e^{-Gamma}
  __shared__ __align__(16) float Bb[CH][132];   // K then V chunk
  __shared__ float egcs[CH];
  const int tid = threadIdx.x;
  const int c = (int)blockIdx.x, bh = (int)blockIdx.y;
  const int b = bh >> 3, h = bh & 7;
  const int t0 = c * CH;

  { // load g chunk [64][64]
    const int gr = tid >> 2, gc0 = (tid & 3) << 4;
    const float* gsrc = G_ + (size_t)(b * Tc + t0 + gr) * (Hc * Mc) + h * Mc + gc0;
#pragma unroll
    for (int j = 0; j < 4; ++j)
      *(float4*)&uls[gr][gc0 + 4 * j] = *(const float4*)(gsrc + 4 * j);
  }
  { // load K chunk [64][128]
    const float* ksrc = K_ + (size_t)(b * Tc + t0) * Dc + h * KDc;
#pragma unroll
    for (int j = 0; j < 8; ++j) {
      int fi = tid + j * 256;
      int r = fi >> 5, cc = (fi & 31) << 2;
      *(float4*)&Bb[r][cc] = *(const float4*)(ksrc + (size_t)r * Dc + cc);
    }
  }
  __syncthreads();
  if (tid < CH) { // column cumsum -> u', e^{GammaC}
    float run = 0.f;
    for (int t = 0; t < CH; ++t) {
      float gv = uls[t][tid];
      run += gv;
      uls[t][tid] = (1.0f - __expf(gv)) * __expf(-run);
    }
    float eg = __expf(run);
    egcs[tid] = eg;
    Gc[((size_t)bh * NC + c) * CH + tid] = eg;
  }
  __syncthreads();
  const size_t stbase = ((size_t)bh * NC + c) * 16384;
  { // dHk[k][m] = egc[m] * sum_tau K[tau][k] u'[tau][m]
    const int k0 = (tid >> 3) << 2, m0 = (tid & 7) << 3;
    float4 acc[4][2];
#pragma unroll
    for (int i = 0; i < 4; ++i) { acc[i][0] = make_float4(0,0,0,0); acc[i][1] = make_float4(0,0,0,0); }
    for (int tau = 0; tau < CH; ++tau) {
      float4 kv = *(const float4*)&Bb[tau][k0];
      float4 u0 = *(const float4*)&uls[tau][m0];
      float4 u1 = *(const float4*)&uls[tau][m0 + 4];
      fma4(kv.x, u0, acc[0][0]); fma4(kv.x, u1, acc[0][1]);
      fma4(kv.y, u0, acc[1][0]); fma4(kv.y, u1, acc[1][1]);
      fma4(kv.z, u0, acc[2][0]); fma4(kv.z, u1, acc[2][1]);
      fma4(kv.w, u0, acc[3][0]); fma4(kv.w, u1, acc[3][1]);
    }
    float4 e0 = *(const float4*)&egcs[m0];
    float4 e1 = *(const float4*)&egcs[m0 + 4];
#pragma unroll
    for (int i = 0; i < 4; ++i) {
      float4 o0, o1;
      o0.x = acc[i][0].x * e0.x; o0.y = acc[i][0].y * e0.y; o0.z = acc[i][0].z * e0.z; o0.w = acc[i][0].w * e0.w;
      o1.x = acc[i][1].x * e1.x; o1.y = acc[i][1].y * e1.y; o1.z = acc[i][1].z * e1.z; o1.w = acc[i][1].w * e1.w;
      float* dst = St + stbase + (size_t)(k0 + i) * 64 + m0;
      *(float4*)dst = o0; *(float4*)(dst + 4) = o1;
    }
  }
  __syncthreads();
  { // load V chunk over K
    const float* vsrc = V_ + (size_t)(b * Tc + t0) * Dc + h * KDc;
#pragma unroll
    for (int j = 0; j < 8; ++j) {
      int fi = tid + j * 256;
      int r = fi >> 5, cc = (fi & 31) << 2;
      *(float4*)&Bb[r][cc] = *(const float4*)(vsrc + (size_t)r * Dc + cc);
    }
  }
  __syncthreads();
  { // dHv[m][v] = egc[m] * sum_tau u'[tau][m] V[tau][v]
    const int m0 = (tid >> 4) << 2, v0 = (tid & 15) << 3;
    float4 acc[4][2];
#pragma unroll
    for (int i = 0; i < 4; ++i) { acc[i][0] = make_float4(0,0,0,0); acc[i][1] = make_float4(0,0,0,0); }
    for (int tau = 0; tau < CH; ++tau) {
      float4 u4 = *(const float4*)&uls[tau][m0];
      float4 va = *(const float4*)&Bb[tau][v0];
      float4 vb = *(const float4*)&Bb[tau][v0 + 4];
      fma4(u4.x, va, acc[0][0]); fma4(u4.x, vb, acc[0][1]);
      fma4(u4.y, va, acc[1][0]); fma4(u4.y, vb, acc[1][1]);
      fma4(u4.z, va, acc[2][0]); fma4(u4.z, vb, acc[2][1]);
      fma4(u4.w, va, acc[3][0]); fma4(u4.w, vb, acc[3][1]);
    }
#pragma unroll
    for (int i = 0; i < 4; ++i) {
      float eg = egcs[m0 + i];
      float4 o0 = acc[i][0], o1 = acc[i][1];
      o0.x *= eg; o0.y *= eg; o0.z *= eg; o0.w *= eg;
      o1.x *= eg; o1.y *= eg; o1.z *= eg; o1.w *= eg;
      float* dst = St + stbase + 8192 + (size_t)(m0 + i) * 128 + v0;
      *(float4*)dst = o0; *(float4*)(dst + 4) = o1;
    }
  }
}

// ---------------- Phase 2: inter-chunk state scan (in place) ----------------
__global__ __launch_bounds__(256)
void scan_phase2(float* St, const float* __restrict__ Gc)
{
  const int tid = threadIdx.x;
  const int bh = (int)blockIdx.x, slice = (int)blockIdx.y;
  const int e0 = slice * 1024 + tid * 4;
  const bool isHk = e0 < 8192;
  float* base = St + (size_t)bh * NC * 16384 + e0;
  const float* gcp = Gc + (size_t)bh * NC * CH;
  float4 run = make_float4(0, 0, 0, 0);
  float4 d = *(float4*)base;
  for (int c = 0; c < NC; ++c) {
    float4 dn = make_float4(0, 0, 0, 0);
    if (c + 1 < NC) dn = *(float4*)(base + (size_t)(c + 1) * 16384);
    float4 ge;
    if (isHk) {
      ge = *(const float4*)(gcp + c * CH + (e0 & 63));
    } else {
      float g1 = gcp[c * CH + ((e0 - 8192) >> 7)];
      ge = make_float4(g1, g1, g1, g1);
    }
    *(float4*)(base + (size_t)c * 16384) = run;
    run.x = fmaf(run.x, ge.x, d.x);
    run.y = fmaf(run.y, ge.y, d.y);
    run.z = fmaf(run.z, ge.z, d.z);
    run.w = fmaf(run.w, ge.w, d.w);
    d = dn;
  }
}

// ---------------- Phase 3: per-chunk outputs ----------------
__global__ __launch_bounds__(256)
void scan_phase3(const float* __restrict__ Q_, const float* __restrict__ K_,
                 const float* __restrict__ V_, const float* __restrict__ G_,
                 const float* __restrict__ St, float* __restrict__ O_)
{
  __shared__ __align__(16) float Qs[CH][132];
  __shared__ __align__(16) float Bf[8704];      // K[64][132] -> Hk0[128][68] -> V[64][132] -> Hv0[64][132]
  __shared__ __align__(16) float us[CH][68];    // u'[tau][m]
  __shared__ __align__(16) float es[CH][68];    // raw g -> e^{Gamma_t[m]}
  __shared__ __align__(16) float Ss[CH][68];    // S masked -> W
  __shared__ __align__(16) float Ps[CH][68];    // A -> P2

  const int tid = threadIdx.x;
  const int c = (int)blockIdx.x, bh = (int)blockIdx.y;
  const int b = bh >> 3, h = bh & 7;
  const int t0 = c * CH;
  const size_t stbase = ((size_t)bh * NC + c) * 16384;

  // 1. load g -> es(raw), Q -> Qs, K -> Bf
  {
    const int gr = tid >> 2, gc0 = (tid & 3) << 4;
    const float* gsrc = G_ + (size_t)(b * Tc + t0 + gr) * (Hc * Mc) + h * Mc + gc0;
#pragma unroll
    for (int j = 0; j < 4; ++j)
      *(float4*)&es[gr][gc0 + 4 * j] = *(const float4*)(gsrc + 4 * j);
    const float* qsrc = Q_ + (size_t)(b * Tc + t0) * Dc + h * KDc;
    const float* ksrc = K_ + (size_t)(b * Tc + t0) * Dc + h * KDc;
#pragma unroll
    for (int j = 0; j < 8; ++j) {
      int fi = tid + j * 256;
      int r = fi >> 5, cc4 = (fi & 31) << 2;
      *(float4*)&Qs[r][cc4] = *(const float4*)(qsrc + (size_t)r * Dc + cc4);
      *(float4*)&Bf[r * 132 + cc4] = *(const float4*)(ksrc + (size_t)r * Dc + cc4);
    }
  }
  __syncthreads();
  // 2a. cumsum (wave 0) -> us, es
  if (tid < CH) {
    float run = 0.f;
    for (int t = 0; t < CH; ++t) {
      float gv = es[t][tid];
      run += gv;
      us[t][tid] = (1.0f - __expf(gv)) * __expf(-run);
      es[t][tid] = __expf(run);
    }
  }
  // 2b. S = Q K^T, causal-masked (incl. diagonal)
  const int tt = tid >> 4, ccg = tid & 15;
  {
    const int tr = tt << 2, tc = ccg << 2;
    float4 acc[4];
#pragma unroll
    for (int i = 0; i < 4; ++i) acc[i] = make_float4(0, 0, 0, 0);
    for (int k = 0; k < KDc; k += 4) {
      float4 kr0 = *(const float4*)&Bf[(tc + 0) * 132 + k];
      float4 kr1 = *(const float4*)&Bf[(tc + 1) * 132 + k];
      float4 kr2 = *(const float4*)&Bf[(tc + 2) * 132 + k];
      float4 kr3 = *(const float4*)&Bf[(tc + 3) * 132 + k];
#pragma unroll
      for (int i = 0; i < 4; ++i) {
        float4 qi = *(const float4*)&Qs[tr + i][k];
        acc[i].x = dot4acc(qi, kr0, acc[i].x);
        acc[i].y = dot4acc(qi, kr1, acc[i].y);
        acc[i].z = dot4acc(qi, kr2, acc[i].z);
        acc[i].w = dot4acc(qi, kr3, acc[i].w);
      }
    }
#pragma unroll
    for (int i = 0; i < 4; ++i) {
      float4 w;
      w.x = (tc + 0 <= tr + i) ? acc[i].x : 0.f;
      w.y = (tc + 1 <= tr + i) ? acc[i].y : 0.f;
      w.z = (tc + 2 <= tr + i) ? acc[i].z : 0.f;
      w.w = (tc + 3 <= tr + i) ? acc[i].w : 0.f;
      *(float4*)&Ss[tr + i][tc] = w;
    }
  }
  __syncthreads();
  // 3. Hk0 -> Bf as [128][68]
  {
#pragma unroll
    for (int j = 0; j < 8; ++j) {
      int fi = tid + j * 256;
      int k = fi >> 4, m4 = (fi & 15) << 2;
      *(float4*)&Bf[k * 68 + m4] = *(const float4*)(St + stbase + (size_t)k * 64 + m4);
    }
  }
  __syncthreads();
  // 4. A[t][m] = SCALE * e^{Gamma} * (Q@Hk0 + S@u') -> Ps
  {
    const int tr = tt << 2, m0 = ccg << 2;
    float4 acc[4];
#pragma unroll
    for (int i = 0; i < 4; ++i) acc[i] = make_float4(0, 0, 0, 0);
    for (int tau = 0; tau < CH; tau += 4) {
      float4 u0 = *(const float4*)&us[tau + 0][m0];
      float4 u1 = *(const float4*)&us[tau + 1][m0];
      float4 u2 = *(const float4*)&us[tau + 2][m0];
      float4 u3 = *(const float4*)&us[tau + 3][m0];
#pragma unroll
      for (int i = 0; i < 4; ++i) {
        float4 s4 = *(const float4*)&Ss[tr + i][tau];
        fma4(s4.x, u0, acc[i]); fma4(s4.y, u1, acc[i]);
        fma4(s4.z, u2, acc[i]); fma4(s4.w, u3, acc[i]);
      }
    }
    for (int k = 0; k < KDc; k += 4) {
      float4 h0 = *(const float4*)&Bf[(k + 0) * 68 + m0];
      float4 h1 = *(const float4*)&Bf[(k + 1) * 68 + m0];
      float4 h2 = *(const float4*)&Bf[(k + 2) * 68 + m0];
      float4 h3 = *(const float4*)&Bf[(k + 3) * 68 + m0];
#pragma unroll
      for (int i = 0; i < 4; ++i) {
        float4 q4 = *(const float4*)&Qs[tr + i][k];
        fma4(q4.x, h0, acc[i]); fma4(q4.y, h1, acc[i]);
        fma4(q4.z, h2, acc[i]); fma4(q4.w, h3, acc[i]);
      }
    }
#pragma unroll
    for (int i = 0; i < 4; ++i) {
      float4 ev = *(const float4*)&es[tr + i][m0];
      float4 ov;
      ov.x = SCALE * ev.x * acc[i].x;
      ov.y = SCALE * ev.y * acc[i].y;
      ov.z = SCALE * ev.z * acc[i].z;
      ov.w = SCALE * ev.w * acc[i].w;
      *(float4*)&Ps[tr + i][m0] = ov;
    }
  }
  __syncthreads();
  // 5. row softmax over m; w = p * e^{Gamma} -> Ss
  {
    const int row = tid >> 2, m0 = (tid & 3) << 4;
    float4 a0 = *(const float4*)&Ps[row][m0];
    float4 a1 = *(const float4*)&Ps[row][m0 + 4];
    float4 a2 = *(const float4*)&Ps[row][m0 + 8];
    float4 a3 = *(const float4*)&Ps[row][m0 + 12];
    float mx = fmaxf(fmaxf(fmaxf(a0.x, a0.y), fmaxf(a0.z, a0.w)),
                     fmaxf(fmaxf(a1.x, a1.y), fmaxf(a1.z, a1.w)));
    mx = fmaxf(mx, fmaxf(fmaxf(fmaxf(a2.x, a2.y), fmaxf(a2.z, a2.w)),
                         fmaxf(fmaxf(a3.x, a3.y), fmaxf(a3.z, a3.w))));
    mx = fmaxf(mx, __shfl_xor(mx, 1, 64));
    mx = fmaxf(mx, __shfl_xor(mx, 2, 64));
    a0.x = __expf(a0.x - mx); a0.y = __expf(a0.y - mx); a0.z = __expf(a0.z - mx); a0.w = __expf(a0.w - mx);
    a1.x = __expf(a1.x - mx); a1.y = __expf(a1.y - mx); a1.z = __expf(a1.z - mx); a1.w = __expf(a1.w - mx);
    a2.x = __expf(a2.x - mx); a2.y = __expf(a2.y - mx); a2.z = __expf(a2.z - mx); a2.w = __expf(a2.w - mx);
    a3.x = __expf(a3.x - mx); a3.y = __expf(a3.y - mx); a3.z = __expf(a3.z - mx); a3.w = __expf(a3.w - mx);
    float sm = a0.x + a0.y + a0.z + a0.w + a1.x + a1.y + a1.z + a1.w
             + a2.x + a2.y + a2.z + a2.w + a3.x + a3.y + a3.z + a3.w;
    sm += __shfl_xor(sm, 1, 64);
    sm += __shfl_xor(sm, 2, 64);
    float inv = 1.0f / sm;
    float4 e0 = *(const float4*)&es[row][m0];
    float4 e1 = *(const float4*)&es[row][m0 + 4];
    float4 e2 = *(const float4*)&es[row][m0 + 8];
    float4 e3 = *(const float4*)&es[row][m0 + 12];
    a0.x *= inv * e0.x; a0.y *= inv * e0.y; a0.z *= inv * e0.z; a0.w *= inv * e0.w;
    a1.x *= inv * e1.x; a1.y *= inv * e1.y; a1.z *= inv * e1.z; a1.w *= inv * e1.w;
    a2.x *= inv * e2.x; a2.y *= inv * e2.y; a2.z *= inv * e2.z; a2.w *= inv * e2.w;
    a3.x *= inv * e3.x; a3.y *= inv * e3.y; a3.z *= inv * e3.z; a3.w *= inv * e3.w;
    *(float4*)&Ss[row][m0] = a0;
    *(float4*)&Ss[row][m0 + 4] = a1;
    *(float4*)&Ss[row][m0 + 8] = a2;
    *(float4*)&Ss[row][m0 + 12] = a3;
  }
  // 6. load V -> Bf (Hk0 dead)
  {
    const float* vsrc = V_ + (size_t)(b * Tc + t0) * Dc + h * KDc;
#pragma unroll
    for (int j = 0; j < 8; ++j) {
      int fi = tid + j * 256;
      int r = fi >> 5, cc4 = (fi & 31) << 2;
      *(float4*)&Bf[r * 132 + cc4] = *(const float4*)(vsrc + (size_t)r * Dc + cc4);
    }
  }
  __syncthreads();
  // 7. P2[t][tau] = sum_m W[t][m] u'[tau][m], masked -> Ps
  {
    const int tr = tt << 2, tc = ccg << 2;
    float4 acc[4];
#pragma unroll
    for (int i = 0; i < 4; ++i) acc[i] = make_float4(0, 0, 0, 0);
    for (int m = 0; m < CH; m += 4) {
      float4 u0 = *(const float4*)&us[tc + 0][m];
      float4 u1 = *(const float4*)&us[tc + 1][m];
      float4 u2 = *(const float4*)&us[tc + 2][m];
      float4 u3 = *(const float4*)&us[tc + 3][m];
#pragma unroll
      for (int i = 0; i < 4; ++i) {
        float4 w4 = *(const float4*)&Ss[tr + i][m];
        acc[i].x = dot4acc(w4, u0, acc[i].x);
        acc[i].y = dot4acc(w4, u1, acc[i].y);
        acc[i].z = dot4acc(w4, u2, acc[i].z);
        acc[i].w = dot4acc(w4, u3, acc[i].w);
      }
    }
#pragma unroll
    for (int i = 0; i < 4; ++i) {
      float4 w;
      w.x = (tc + 0 <= tr + i) ? acc[i].x : 0.f;
      w.y = (tc + 1 <= tr + i) ? acc[i].y : 0.f;
      w.z = (tc + 2 <= tr + i) ? acc[i].z : 0.f;
      w.w = (tc + 3 <= tr + i) ? acc[i].w : 0.f;
      *(float4*)&Ps[tr + i][tc] = w;
    }
  }
  __syncthreads();
  // 8. O = P2 @ V  (accumulate in regs)
  const int tr = tt << 2, v0 = ccg << 3;
  float4 accO[4][2];
#pragma unroll
  for (int i = 0; i < 4; ++i) { accO[i][0] = make_float4(0,0,0,0); accO[i][1] = make_float4(0,0,0,0); }
  for (int tau = 0; tau < CH; tau += 4) {
    float4 pr[4];
#pragma unroll
    for (int i = 0; i < 4; ++i) pr[i] = *(const float4*)&Ps[tr + i][tau];
#pragma unroll
    for (int d = 0; d < 4; ++d) {
      float4 va = *(const float4*)&Bf[(tau + d) * 132 + v0];
      float4 vb = *(const float4*)&Bf[(tau + d) * 132 + v0 + 4];
#pragma unroll
      for (int i = 0; i < 4; ++i) {
        float p = (d == 0) ? pr[i].x : (d == 1) ? pr[i].y : (d == 2) ? pr[i].z : pr[i].w;
        fma4(p, va, accO[i][0]); fma4(p, vb, accO[i][1]);
      }
    }
  }
  __syncthreads();
  // 9. Hv0 -> Bf
  {
#pragma unroll
    for (int j = 0; j < 8; ++j) {
      int fi = tid + j * 256;
      int m = fi >> 5, c4 = (fi & 31) << 2;
      *(float4*)&Bf[m * 132 + c4] = *(const float4*)(St + stbase + 8192 + (size_t)m * 128 + c4);
    }
  }
  __syncthreads();
  // 10. O += W @ Hv0 ; store
  for (int m = 0; m < CH; m += 4) {
    float4 wr[4];
#pragma unroll
    for (int i = 0; i < 4; ++i) wr[i] = *(const float4*)&Ss[tr + i][m];
#pragma unroll
    for (int d = 0; d < 4; ++d) {
      float4 ha = *(const float4*)&Bf[(m + d) * 132 + v0];
      float4 hb = *(const float4*)&Bf[(m + d) * 132 + v0 + 4];
#pragma unroll
      for (int i = 0; i < 4; ++i) {
        float w = (d == 0) ? wr[i].x : (d == 1) ? wr[i].y : (d == 2) ? wr[i].z : wr[i].w;
        fma4(w, ha, accO[i][0]); fma4(w, hb, accO[i][1]);
      }
    }
  }
#pragma unroll
  for (int i = 0; i < 4; ++i) {
    float* dst = O_ + (size_t)(b * Tc + t0 + tr + i) * Dc + h * KDc + v0;
    *(float4*)dst = accO[i][0];
    *(float4*)(dst + 4) = accO[i][1];
  }
}

// ---------------- post: swish -> RMSNorm, bf16 out ----------------
__global__ __launch_bounds__(256)
void post_rms(const float* __restrict__ Oin, const float* __restrict__ gw,
              unsigned short* __restrict__ Nout)
{
  __shared__ float red[4];
  const int row = (int)blockIdx.x, tid = threadIdx.x;
  const float4 o4 = *(const float4*)(Oin + (size_t)row * Dc + tid * 4);
  float4 s4;
  s4.x = swishf(o4.x); s4.y = swishf(o4.y); s4.z = swishf(o4.z); s4.w = swishf(o4.w);
  float ss = s4.x * s4.x + s4.y * s4.y + s4.z * s4.z + s4.w * s4.w;
#pragma unroll
  for (int off = 32; off > 0; off >>= 1) ss += __shfl_xor(ss, off, 64);
  if ((tid & 63) == 0) red[tid >> 6] = ss;
  __syncthreads();
  float total = red[0] + red[1] + red[2] + red[3];
  float rms = rsqrtf(total * (1.0f / Dc) + 1e-5f);
  const float4 g4 = *(const float4*)(gw + tid * 4);
  ushort4 h;
  h.x = f2bf(s4.x * rms * g4.x);
  h.y = f2bf(s4.y * rms * g4.y);
  h.z = f2bf(s4.z * rms * g4.z);
  h.w = f2bf(s4.w * rms * g4.w);
  *(ushort4*)(Nout + (size_t)row * Dc + tid * 4) = h;
}

} // namespace

extern "C" void kernel_launch(void* const* d_in, const int* in_sizes, int n_in,
                              void* d_out, int out_size, void* d_ws, size_t ws_size,
                              hipStream_t stream)
{
  const float* x  = (const float*)d_in[0];
  const float* Wq = (const float*)d_in[1];
  const float* Wk = (const float*)d_in[2];
  const float* Wv = (const float*)d_in[3];
  const float* Wf = (const float*)d_in[4];
  const float* Wo = (const float*)d_in[5];
  const float* gw = (const float*)d_in[6];
  float* out = (float*)d_out;

  // workspace (MB): qb 0-16, kb 16-32, vb 32-48, gb 48-56, st 56-88, gcb 88-89, ob 89-105,
  // wob 105-107.  bf16 xb (56-64) + wqkvf (64-71) live inside st region (dead until phase1).
  // nbb aliases qb (dead after phase3).
  char* ws = (char*)d_ws;
  const size_t MB = 1ull << 20;
  float* qb  = (float*)(ws);
  float* kb  = (float*)(ws + 16 * MB);
  float* vb  = (float*)(ws + 32 * MB);
  float* gb  = (float*)(ws + 48 * MB);
  float* st  = (float*)(ws + 56 * MB);
  float* gcb = (float*)(ws + 88 * MB);
  float* ob  = (float*)(ws + 89 * MB);
  unsigned short* xb    = (unsigned short*)(ws + 56 * MB);
  unsigned short* wqkvf = (unsigned short*)(ws + 64 * MB);
  unsigned short* wob   = (unsigned short*)(ws + 105 * MB);
  unsigned short* nbb   = (unsigned short*)(ws); // alias qb

  dim3 blk(256);
  cvt_bf16_all<<<dim3(4352), blk, 0, stream>>>(x, Wq, Wk, Wv, Wf, Wo, xb, wqkvf, wob);
  gemm_bt<1><<<dim3(28, 32), blk, 0, stream>>>(xb, wqkvf, qb, kb, vb, gb);
  scan_phase1<<<dim3(NC, 16), blk, 0, stream>>>(kb, vb, gb, st, gcb);
  scan_phase2<<<dim3(16, 16), blk, 0, stream>>>(st, gcb);
  scan_phase3<<<dim3(NC, 16), blk, 0, stream>>>(qb, kb, vb, gb, st, ob);
  post_rms<<<dim3(ROWS), blk, 0, stream>>>(ob, gw, nbb);
  gemm_bt<0><<<dim3(8, 32), blk, 0, stream>>>(nbb, wob, out, nullptr, nullptr, nullptr);
}

// Round 13
// 266.934 us; speedup vs baseline: 19.1747x; 1.1920x over previous
//
#include <hip/hip_runtime.h>
#include <cstddef>
#include <cstdint>

namespace {

constexpr int Bc = 2, Tc = 2048, Dc = 1024, Hc = 8, Mc = 64, KDc = 128;
constexpr int ROWS = Bc * Tc; // 4096
constexpr int CH = 64, NC = Tc / CH; // chunk len, 32 chunks
constexpr float SCALE = 0.08838834764831845f; // 128^-0.5
constexpr float GATE_NORM_INV = 1.0f / 16.0f;

typedef __attribute__((ext_vector_type(8))) short bf16x8;
typedef __attribute__((ext_vector_type(4))) float f32x4;

__device__ __forceinline__ float swishf(float x) {
  return x / (1.0f + __expf(-x));
}
__device__ __forceinline__ float logsig16f(float x) {
  return (fminf(x, 0.f) - __logf(1.f + __expf(-fabsf(x)))) * GATE_NORM_INV;
}
__device__ __forceinline__ unsigned short f2bf(float f) {
  union { float f; unsigned u; } v; v.f = f;
  unsigned r = v.u + 0x7FFF + ((v.u >> 16) & 1); // RNE
  return (unsigned short)(r >> 16);
}
__device__ __forceinline__ void fma4(float a, const float4& b, float4& acc) {
  acc.x = fmaf(a, b.x, acc.x); acc.y = fmaf(a, b.y, acc.y);
  acc.z = fmaf(a, b.z, acc.z); acc.w = fmaf(a, b.w, acc.w);
}
__device__ __forceinline__ float getc(const float4& v, int c) {
  return (c == 0) ? v.x : (c == 1) ? v.y : (c == 2) ? v.z : v.w;
}

#define GLOAD_LDS16(g, l) __builtin_amdgcn_global_load_lds( \
    (const __attribute__((address_space(1))) unsigned int*)(g), \
    (__attribute__((address_space(3))) unsigned int*)(l), 16, 0, 0)

// ---------------- one-shot f32 -> bf16 conversion (x, Wq|Wk|Wv|Wf concat, Wo) ----------------
__global__ __launch_bounds__(256)
void cvt_bf16_all(const float* __restrict__ x, const float* __restrict__ wq,
                  const float* __restrict__ wk, const float* __restrict__ wv,
                  const float* __restrict__ wf, const float* __restrict__ wo,
                  unsigned short* __restrict__ xb, unsigned short* __restrict__ wqkvf,
                  unsigned short* __restrict__ wob)
{
  long e = ((long)blockIdx.x * 256 + threadIdx.x) * 8;
  const float* src; unsigned short* dst; long off;
  if (e < 4194304L)      { src = x;  dst = xb;              off = e; }
  else if (e < 5242880L) { src = wq; dst = wqkvf;           off = e - 4194304L; }
  else if (e < 6291456L) { src = wk; dst = wqkvf + 1048576; off = e - 5242880L; }
  else if (e < 7340032L) { src = wv; dst = wqkvf + 2097152; off = e - 6291456L; }
  else if (e < 7864320L) { src = wf; dst = wqkvf + 3145728; off = e - 7340032L; }
  else                   { src = wo; dst = wob;             off = e - 7864320L; }
  float4 a = *(const float4*)(src + off);
  float4 b = *(const float4*)(src + off + 4);
  ushort4 h0, h1;
  h0.x = f2bf(a.x); h0.y = f2bf(a.y); h0.z = f2bf(a.z); h0.w = f2bf(a.w);
  h1.x = f2bf(b.x); h1.y = f2bf(b.y); h1.z = f2bf(b.z); h1.w = f2bf(b.w);
  *(ushort4*)(dst + off) = h0;
  *(ushort4*)(dst + off + 4) = h1;
}

// ---------------- bf16 MFMA GEMM: C = A @ B^T (validated round 11) ----------------
template<int EPI>
__global__ __launch_bounds__(256)
void gemm_bt(const unsigned short* __restrict__ A, const unsigned short* __restrict__ Bm,
             float* __restrict__ C0, float* __restrict__ C1,
             float* __restrict__ C2, float* __restrict__ C3)
{
  __shared__ __align__(16) unsigned short As[128 * 32];
  __shared__ __align__(16) unsigned short Bs[128 * 32];
  const int tid = threadIdx.x;
  const int lane = tid & 63, w = tid >> 6;
  const int bcol = (int)blockIdx.x, brow = (int)blockIdx.y;
  const int wr = w >> 1, wc = w & 1;
  const int lrow = lane & 15, lk8 = (lane >> 4) << 3;

  const int srow = w * 32 + (lane >> 2);
  const int scol = (lane & 3) << 3;
  const unsigned short* Ag0 = A + (size_t)(brow * 128 + srow) * 1024 + scol;
  const unsigned short* Ag1 = Ag0 + (size_t)16 * 1024;
  const unsigned short* Bg0 = Bm + (size_t)(bcol * 128 + srow) * 1024 + scol;
  const unsigned short* Bg1 = Bg0 + (size_t)16 * 1024;
  unsigned short* Al0 = As + w * 1024;
  unsigned short* Al1 = As + w * 1024 + 512;
  unsigned short* Bl0 = Bs + w * 1024;
  unsigned short* Bl1 = Bs + w * 1024 + 512;

  f32x4 acc[4][4];
#pragma unroll
  for (int i = 0; i < 4; ++i)
#pragma unroll
    for (int j = 0; j < 4; ++j)
#pragma unroll
      for (int r = 0; r < 4; ++r) acc[i][j][r] = 0.f;

  for (int k0 = 0; k0 < 1024; k0 += 32) {
    __syncthreads();
    GLOAD_LDS16(Ag0 + k0, Al0);
    GLOAD_LDS16(Ag1 + k0, Al1);
    GLOAD_LDS16(Bg0 + k0, Bl0);
    GLOAD_LDS16(Bg1 + k0, Bl1);
    __syncthreads();

    bf16x8 av[4], bv[4];
#pragma unroll
    for (int i = 0; i < 4; ++i)
      av[i] = *(const bf16x8*)&As[(wr * 64 + i * 16 + lrow) * 32 + lk8];
#pragma unroll
    for (int j = 0; j < 4; ++j)
      bv[j] = *(const bf16x8*)&Bs[(wc * 64 + j * 16 + lrow) * 32 + lk8];
#pragma unroll
    for (int i = 0; i < 4; ++i)
#pragma unroll
      for (int j = 0; j < 4; ++j)
        acc[i][j] = __builtin_amdgcn_mfma_f32_16x16x32_bf16(av[i], bv[j], acc[i][j], 0, 0, 0);
  }

#pragma unroll
  for (int i = 0; i < 4; ++i) {
#pragma unroll
    for (int j = 0; j < 4; ++j) {
#pragma unroll
      for (int r = 0; r < 4; ++r) {
        int row = brow * 128 + wr * 64 + i * 16 + ((lane >> 4) << 2) + r;
        int n   = bcol * 128 + wc * 64 + j * 16 + (lane & 15);
        float v = acc[i][j][r];
        if (EPI == 0) {
          C0[(size_t)row * 1024 + n] = v;
        } else {
          if (n < 1024)      C0[(size_t)row * 1024 + n]          = swishf(v);
          else if (n < 2048) C1[(size_t)row * 1024 + (n - 1024)] = swishf(v);
          else if (n < 3072) C2[(size_t)row * 1024 + (n - 2048)] = swishf(v);
          else               C3[(size_t)row * 512  + (n - 3072)] = logsig16f(v);
        }
      }
    }
  }
}

// ---------------- Phase 1: per-chunk local state deltas (TRANSPOSED outputs) ----------------
// St[bh][c] = [ dHkT (64 m x 128 k) | dHvT (128 v x 64 m) ]
__global__ __launch_bounds__(256)
void scan_phase1(const float* __restrict__ K_, const float* __restrict__ V_,
                 const float* __restrict__ G_, float* __restrict__ St,
                 float* __restrict__ Gc)
{
  __shared__ __align__(16) float uls[CH][68];
  __shared__ __align__(16) float Bb[CH][132];
  __shared__ float egcs[CH];
  const int tid = threadIdx.x;
  const int c = (int)blockIdx.x, bh = (int)blockIdx.y;
  const int b = bh >> 3, h = bh & 7;
  const int t0 = c * CH;

  { // load g chunk
    const int gr = tid >> 2, gc0 = (tid & 3) << 4;
    const float* gsrc = G_ + (size_t)(b * Tc + t0 + gr) * (Hc * Mc) + h * Mc + gc0;
#pragma unroll
    for (int j = 0; j < 4; ++j)
      *(float4*)&uls[gr][gc0 + 4 * j] = *(const float4*)(gsrc + 4 * j);
  }
  { // load K chunk
    const float* ksrc = K_ + (size_t)(b * Tc + t0) * Dc + h * KDc;
#pragma unroll
    for (int j = 0; j < 8; ++j) {
      int fi = tid + j * 256;
      int r = fi >> 5, cc = (fi & 31) << 2;
      *(float4*)&Bb[r][cc] = *(const float4*)(ksrc + (size_t)r * Dc + cc);
    }
  }
  __syncthreads();
  if (tid < CH) {
    float run = 0.f;
    for (int t = 0; t < CH; ++t) {
      float gv = uls[t][tid];
      run += gv;
      uls[t][tid] = (1.0f - __expf(gv)) * __expf(-run);
    }
    float eg = __expf(run);
    egcs[tid] = eg;
    Gc[((size_t)bh * NC + c) * CH + tid] = eg;
  }
  __syncthreads();
  const size_t stbase = ((size_t)bh * NC + c) * 16384;
  { // dHkT[m][k] = egc[m] * sum_tau K[tau][k] u'[tau][m]
    const int k0 = (tid >> 3) << 2, m0 = (tid & 7) << 3;
    float4 acc[4][2];
#pragma unroll
    for (int i = 0; i < 4; ++i) { acc[i][0] = make_float4(0,0,0,0); acc[i][1] = make_float4(0,0,0,0); }
    for (int tau = 0; tau < CH; ++tau) {
      float4 kv = *(const float4*)&Bb[tau][k0];
      float4 u0 = *(const float4*)&uls[tau][m0];
      float4 u1 = *(const float4*)&uls[tau][m0 + 4];
      fma4(kv.x, u0, acc[0][0]); fma4(kv.x, u1, acc[0][1]);
      fma4(kv.y, u0, acc[1][0]); fma4(kv.y, u1, acc[1][1]);
      fma4(kv.z, u0, acc[2][0]); fma4(kv.z, u1, acc[2][1]);
      fma4(kv.w, u0, acc[3][0]); fma4(kv.w, u1, acc[3][1]);
    }
#pragma unroll
    for (int jm = 0; jm < 8; ++jm) {
      int m = m0 + jm, hh = jm >> 2, cc = jm & 3;
      float eg = egcs[m];
      float4 o;
      o.x = getc(acc[0][hh], cc) * eg;
      o.y = getc(acc[1][hh], cc) * eg;
      o.z = getc(acc[2][hh], cc) * eg;
      o.w = getc(acc[3][hh], cc) * eg;
      *(float4*)(St + stbase + (size_t)m * 128 + k0) = o;
    }
  }
  __syncthreads();
  { // load V chunk over K
    const float* vsrc = V_ + (size_t)(b * Tc + t0) * Dc + h * KDc;
#pragma unroll
    for (int j = 0; j < 8; ++j) {
      int fi = tid + j * 256;
      int r = fi >> 5, cc = (fi & 31) << 2;
      *(float4*)&Bb[r][cc] = *(const float4*)(vsrc + (size_t)r * Dc + cc);
    }
  }
  __syncthreads();
  { // dHvT[v][m] = egc[m] * sum_tau u'[tau][m] V[tau][v]
    const int m0 = (tid >> 4) << 2, v0 = (tid & 15) << 3;
    float4 acc[4][2];
#pragma unroll
    for (int i = 0; i < 4; ++i) { acc[i][0] = make_float4(0,0,0,0); acc[i][1] = make_float4(0,0,0,0); }
    for (int tau = 0; tau < CH; ++tau) {
      float4 u4 = *(const float4*)&uls[tau][m0];
      float4 va = *(const float4*)&Bb[tau][v0];
      float4 vb = *(const float4*)&Bb[tau][v0 + 4];
      fma4(u4.x, va, acc[0][0]); fma4(u4.x, vb, acc[0][1]);
      fma4(u4.y, va, acc[1][0]); fma4(u4.y, vb, acc[1][1]);
      fma4(u4.z, va, acc[2][0]); fma4(u4.z, vb, acc[2][1]);
      fma4(u4.w, va, acc[3][0]); fma4(u4.w, vb, acc[3][1]);
    }
    float4 e4 = *(const float4*)&egcs[m0];
#pragma unroll
    for (int jv = 0; jv < 8; ++jv) {
      int v = v0 + jv, hh = jv >> 2, cc = jv & 3;
      float4 o;
      o.x = getc(acc[0][hh], cc) * e4.x;
      o.y = getc(acc[1][hh], cc) * e4.y;
      o.z = getc(acc[2][hh], cc) * e4.z;
      o.w = getc(acc[3][hh], cc) * e4.w;
      *(float4*)(St + stbase + 8192 + (size_t)v * 64 + m0) = o;
    }
  }
}

// ---------------- Phase 2: inter-chunk state scan (transposed layouts) ----------------
__global__ __launch_bounds__(256)
void scan_phase2(float* St, const float* __restrict__ Gc)
{
  const int tid = threadIdx.x;
  const int bh = (int)blockIdx.x, slice = (int)blockIdx.y;
  const int e0 = slice * 1024 + tid * 4;
  const bool isHk = e0 < 8192;
  float* base = St + (size_t)bh * NC * 16384 + e0;
  const float* gcp = Gc + (size_t)bh * NC * CH;
  float4 run = make_float4(0, 0, 0, 0);
  float4 d = *(float4*)base;
  for (int c = 0; c < NC; ++c) {
    float4 dn = make_float4(0, 0, 0, 0);
    if (c + 1 < NC) dn = *(float4*)(base + (size_t)(c + 1) * 16384);
    float4 ge;
    if (isHk) { // HkT [m][k]: m = e0>>7, broadcast
      float g1 = gcp[c * CH + (e0 >> 7)];
      ge = make_float4(g1, g1, g1, g1);
    } else {    // HvT [v][m]: m = (e0-8192)&63, vector
      ge = *(const float4*)(gcp + c * CH + ((e0 - 8192) & 63));
    }
    *(float4*)(base + (size_t)c * 16384) = run;
    run.x = fmaf(run.x, ge.x, d.x);
    run.y = fmaf(run.y, ge.y, d.y);
    run.z = fmaf(run.z, ge.z, d.z);
    run.w = fmaf(run.w, ge.w, d.w);
    d = dn;
  }
}

// ---------------- Phase 3: per-chunk outputs, MFMA ----------------
// 4 waves; wave w owns rows t = w*16 .. w*16+15 of the chunk.
__global__ __launch_bounds__(256)
void scan_phase3(const float* __restrict__ Q_, const float* __restrict__ K_,
                 const float* __restrict__ V_, const float* __restrict__ G_,
                 const float* __restrict__ St, float* __restrict__ O_)
{
  __shared__ __align__(16) unsigned short Qb[64 * 136];   // [t][k]
  __shared__ __align__(16) unsigned short buf2[128 * 72]; // Kb/HkTb as [64][136]; VbT/HvTb as [128][72]
  __shared__ __align__(16) unsigned short Sb[64 * 72];    // masked S [t][tau]
  __shared__ __align__(16) unsigned short Wb[64 * 72];    // W [t][m]
  __shared__ __align__(16) unsigned short P2b[64 * 72];   // masked P2 [t][tau]
  __shared__ __align__(16) unsigned short ub[64 * 72];    // u' [tau][m]
  __shared__ __align__(16) unsigned short ubt[64 * 72];   // u'^T [m][tau]
  __shared__ __align__(16) float es[64 * 68];             // g -> e^{Gamma_t[m]}

  const int tid = threadIdx.x, lane = tid & 63, w = tid >> 6;
  const int c = (int)blockIdx.x, bh = (int)blockIdx.y;
  const int b = bh >> 3, h = bh & 7;
  const int t0 = c * CH;
  const size_t stbase = ((size_t)bh * NC + c) * 16384;
  const int col = lane & 15, rb = (lane >> 4) << 2;   // D-layout: row=rb+r, col
  const int arow = lane & 15, ak = (lane >> 4) << 3;  // A/B frag: row, k-slice

  // stage Qb, Kb(buf2), g(es)
  {
    const int r = tid >> 2, cs = (tid & 3) << 5;
    const float* qs = Q_ + (size_t)(b * Tc + t0 + r) * Dc + h * KDc + cs;
    const float* ks = K_ + (size_t)(b * Tc + t0 + r) * Dc + h * KDc + cs;
#pragma unroll
    for (int q = 0; q < 8; ++q) {
      float4 a = *(const float4*)(qs + q * 4);
      ushort4 ha; ha.x = f2bf(a.x); ha.y = f2bf(a.y); ha.z = f2bf(a.z); ha.w = f2bf(a.w);
      *(ushort4*)&Qb[r * 136 + cs + q * 4] = ha;
      float4 bq = *(const float4*)(ks + q * 4);
      ushort4 hb; hb.x = f2bf(bq.x); hb.y = f2bf(bq.y); hb.z = f2bf(bq.z); hb.w = f2bf(bq.w);
      *(ushort4*)&buf2[r * 136 + cs + q * 4] = hb;
    }
    const int gcs = (tid & 3) << 4;
    const float* gs = G_ + (size_t)(b * Tc + t0 + r) * (Hc * Mc) + h * Mc + gcs;
#pragma unroll
    for (int q = 0; q < 4; ++q)
      *(float4*)&es[r * 68 + gcs + q * 4] = *(const float4*)(gs + q * 4);
  }
  __syncthreads();
  // cumsum: es raw g -> e^{Gamma}; u' -> ub [tau][m] and ubt [m][tau]
  if (tid < 64) {
    float run = 0.f;
    ushort4 pk;
    for (int t = 0; t < 64; ++t) {
      float gv = es[t * 68 + tid];
      run += gv;
      float uu = (1.0f - __expf(gv)) * __expf(-run);
      es[t * 68 + tid] = __expf(run);
      unsigned short ubf = f2bf(uu);
      ub[t * 72 + tid] = ubf;
      ((unsigned short*)&pk)[t & 3] = ubf;
      if ((t & 3) == 3) *(ushort4*)&ubt[tid * 72 + (t - 3)] = pk;
    }
  }
  __syncthreads();
  // S = Q @ K^T (mask) -> Sb
  {
    f32x4 s[4];
#pragma unroll
    for (int j = 0; j < 4; ++j)
#pragma unroll
      for (int r = 0; r < 4; ++r) s[j][r] = 0.f;
#pragma unroll
    for (int k0 = 0; k0 < 128; k0 += 32) {
      bf16x8 aq = *(const bf16x8*)&Qb[(w * 16 + arow) * 136 + k0 + ak];
#pragma unroll
      for (int j = 0; j < 4; ++j) {
        bf16x8 bk = *(const bf16x8*)&buf2[(j * 16 + arow) * 136 + k0 + ak];
        s[j] = __builtin_amdgcn_mfma_f32_16x16x32_bf16(aq, bk, s[j], 0, 0, 0);
      }
    }
#pragma unroll
    for (int j = 0; j < 4; ++j)
#pragma unroll
      for (int r = 0; r < 4; ++r) {
        int t = w * 16 + rb + r, tau = j * 16 + col;
        Sb[t * 72 + tau] = f2bf((tau <= t) ? s[j][r] : 0.f);
      }
  }
  __syncthreads(); // all waves done reading Kb
  // stage HkT -> buf2 [64][136]
  {
    const int r = tid >> 2, cs = (tid & 3) << 5;
    const float* hs = St + stbase + (size_t)r * 128 + cs;
#pragma unroll
    for (int q = 0; q < 8; ++q) {
      float4 a = *(const float4*)(hs + q * 4);
      ushort4 ha; ha.x = f2bf(a.x); ha.y = f2bf(a.y); ha.z = f2bf(a.z); ha.w = f2bf(a.w);
      *(ushort4*)&buf2[r * 136 + cs + q * 4] = ha;
    }
  }
  __syncthreads();
  // A = S@u'(ubt) + Q@Hk0(buf2); scale; softmax; W -> Wb
  {
    f32x4 a4[4];
#pragma unroll
    for (int j = 0; j < 4; ++j)
#pragma unroll
      for (int r = 0; r < 4; ++r) a4[j][r] = 0.f;
#pragma unroll
    for (int k0 = 0; k0 < 64; k0 += 32) {
      bf16x8 as_ = *(const bf16x8*)&Sb[(w * 16 + arow) * 72 + k0 + ak];
#pragma unroll
      for (int j = 0; j < 4; ++j) {
        bf16x8 bu = *(const bf16x8*)&ubt[(j * 16 + arow) * 72 + k0 + ak];
        a4[j] = __builtin_amdgcn_mfma_f32_16x16x32_bf16(as_, bu, a4[j], 0, 0, 0);
      }
    }
#pragma unroll
    for (int k0 = 0; k0 < 128; k0 += 32) {
      bf16x8 aq = *(const bf16x8*)&Qb[(w * 16 + arow) * 136 + k0 + ak];
#pragma unroll
      for (int j = 0; j < 4; ++j) {
        bf16x8 bh_ = *(const bf16x8*)&buf2[(j * 16 + arow) * 136 + k0 + ak];
        a4[j] = __builtin_amdgcn_mfma_f32_16x16x32_bf16(aq, bh_, a4[j], 0, 0, 0);
      }
    }
    float er[4][4], lg[4][4];
#pragma unroll
    for (int j = 0; j < 4; ++j)
#pragma unroll
      for (int r = 0; r < 4; ++r) {
        er[j][r] = es[(w * 16 + rb + r) * 68 + j * 16 + col];
        lg[j][r] = SCALE * er[j][r] * a4[j][r];
      }
    float mx[4] = {-1e30f, -1e30f, -1e30f, -1e30f};
#pragma unroll
    for (int j = 0; j < 4; ++j)
#pragma unroll
      for (int r = 0; r < 4; ++r) mx[r] = fmaxf(mx[r], lg[j][r]);
#pragma unroll
    for (int bx = 1; bx < 16; bx <<= 1)
#pragma unroll
      for (int r = 0; r < 4; ++r) mx[r] = fmaxf(mx[r], __shfl_xor(mx[r], bx, 64));
    float se[4] = {0.f, 0.f, 0.f, 0.f}, p[4][4];
#pragma unroll
    for (int j = 0; j < 4; ++j)
#pragma unroll
      for (int r = 0; r < 4; ++r) { p[j][r] = __expf(lg[j][r] - mx[r]); se[r] += p[j][r]; }
#pragma unroll
    for (int bx = 1; bx < 16; bx <<= 1)
#pragma unroll
      for (int r = 0; r < 4; ++r) se[r] += __shfl_xor(se[r], bx, 64);
#pragma unroll
    for (int j = 0; j < 4; ++j)
#pragma unroll
      for (int r = 0; r < 4; ++r) {
        float wv = p[j][r] / se[r] * er[j][r];
        Wb[(w * 16 + rb + r) * 72 + j * 16 + col] = f2bf(wv);
      }
  }
  __syncthreads(); // all waves done reading HkT
  // stage VbT -> buf2 [128 v][72 tau]  (transpose)
  {
#pragma unroll
    for (int q = 0; q < 8; ++q) {
      int fi = tid + q * 256;
      int tau = fi & 63, v0 = (fi >> 6) << 2;
      float4 a = *(const float4*)(V_ + (size_t)(b * Tc + t0 + tau) * Dc + h * KDc + v0);
      buf2[(v0 + 0) * 72 + tau] = f2bf(a.x);
      buf2[(v0 + 1) * 72 + tau] = f2bf(a.y);
      buf2[(v0 + 2) * 72 + tau] = f2bf(a.z);
      buf2[(v0 + 3) * 72 + tau] = f2bf(a.w);
    }
  }
  // P2 = W @ u'(ub), mask -> P2b  (independent of buf2)
  {
    f32x4 p2[4];
#pragma unroll
    for (int j = 0; j < 4; ++j)
#pragma unroll
      for (int r = 0; r < 4; ++r) p2[j][r] = 0.f;
#pragma unroll
    for (int k0 = 0; k0 < 64; k0 += 32) {
      bf16x8 aw = *(const bf16x8*)&Wb[(w * 16 + arow) * 72 + k0 + ak];
#pragma unroll
      for (int j = 0; j < 4; ++j) {
        bf16x8 bu = *(const bf16x8*)&ub[(j * 16 + arow) * 72 + k0 + ak];
        p2[j] = __builtin_amdgcn_mfma_f32_16x16x32_bf16(aw, bu, p2[j], 0, 0, 0);
      }
    }
#pragma unroll
    for (int j = 0; j < 4; ++j)
#pragma unroll
      for (int r = 0; r < 4; ++r) {
        int t = w * 16 + rb + r, tau = j * 16 + col;
        P2b[t * 72 + tau] = f2bf((tau <= t) ? p2[j][r] : 0.f);
      }
  }
  __syncthreads();
  // O = P2 @ V  (VbT in buf2)
  f32x4 o8[8];
#pragma unroll
  for (int j = 0; j < 8; ++j)
#pragma unroll
    for (int r = 0; r < 4; ++r) o8[j][r] = 0.f;
#pragma unroll
  for (int k0 = 0; k0 < 64; k0 += 32) {
    bf16x8 ap = *(const bf16x8*)&P2b[(w * 16 + arow) * 72 + k0 + ak];
#pragma unroll
    for (int j = 0; j < 8; ++j) {
      bf16x8 bv = *(const bf16x8*)&buf2[(j * 16 + arow) * 72 + k0 + ak];
      o8[j] = __builtin_amdgcn_mfma_f32_16x16x32_bf16(ap, bv, o8[j], 0, 0, 0);
    }
  }
  __syncthreads(); // all waves done reading VbT
  // stage HvT -> buf2 [128 v][72 m]
  {
    const int r = tid >> 1, cs = (tid & 1) << 5;
    const float* hs = St + stbase + 8192 + (size_t)r * 64 + cs;
#pragma unroll
    for (int q = 0; q < 8; ++q) {
      float4 a = *(const float4*)(hs + q * 4);
      ushort4 ha; ha.x = f2bf(a.x); ha.y = f2bf(a.y); ha.z = f2bf(a.z); ha.w = f2bf(a.w);
      *(ushort4*)&buf2[r * 72 + cs + q * 4] = ha;
    }
  }
  __syncthreads();
  // O += W @ Hv0 (HvT in buf2)
#pragma unroll
  for (int k0 = 0; k0 < 64; k0 += 32) {
    bf16x8 aw = *(const bf16x8*)&Wb[(w * 16 + arow) * 72 + k0 + ak];
#pragma unroll
    for (int j = 0; j < 8; ++j) {
      bf16x8 bhv = *(const bf16x8*)&buf2[(j * 16 + arow) * 72 + k0 + ak];
      o8[j] = __builtin_amdgcn_mfma_f32_16x16x32_bf16(aw, bhv, o8[j], 0, 0, 0);
    }
  }
  // epilogue: write O f32
#pragma unroll
  for (int j = 0; j < 8; ++j)
#pragma unroll
    for (int r = 0; r < 4; ++r)
      O_[(size_t)(b * Tc + t0 + w * 16 + rb + r) * Dc + h * KDc + j * 16 + col] = o8[j][r];
}

// ---------------- post: swish -> RMSNorm, bf16 out ----------------
__global__ __launch_bounds__(256)
void post_rms(const float* __restrict__ Oin, const float* __restrict__ gw,
              unsigned short* __restrict__ Nout)
{
  __shared__ float red[4];
  const int row = (int)blockIdx.x, tid = threadIdx.x;
  const float4 o4 = *(const float4*)(Oin + (size_t)row * Dc + tid * 4);
  float4 s4;
  s4.x = swishf(o4.x); s4.y = swishf(o4.y); s4.z = swishf(o4.z); s4.w = swishf(o4.w);
  float ss = s4.x * s4.x + s4.y * s4.y + s4.z * s4.z + s4.w * s4.w;
#pragma unroll
  for (int off = 32; off > 0; off >>= 1) ss += __shfl_xor(ss, off, 64);
  if ((tid & 63) == 0) red[tid >> 6] = ss;
  __syncthreads();
  float total = red[0] + red[1] + red[2] + red[3];
  float rms = rsqrtf(total * (1.0f / Dc) + 1e-5f);
  const float4 g4 = *(const float4*)(gw + tid * 4);
  ushort4 h;
  h.x = f2bf(s4.x * rms * g4.x);
  h.y = f2bf(s4.y * rms * g4.y);
  h.z = f2bf(s4.z * rms * g4.z);
  h.w = f2bf(s4.w * rms * g4.w);
  *(ushort4*)(Nout + (size_t)row * Dc + tid * 4) = h;
}

} // namespace

extern "C" void kernel_launch(void* const* d_in, const int* in_sizes, int n_in,
                              void* d_out, int out_size, void* d_ws, size_t ws_size,
                              hipStream_t stream)
{
  const float* x  = (const float*)d_in[0];
  const float* Wq = (const float*)d_in[1];
  const float* Wk = (const float*)d_in[2];
  const float* Wv = (const float*)d_in[3];
  const float* Wf = (const float*)d_in[4];
  const float* Wo = (const float*)d_in[5];
  const float* gw = (const float*)d_in[6];
  float* out = (float*)d_out;

  char* ws = (char*)d_ws;
  const size_t MB = 1ull << 20;
  float* qb  = (float*)(ws);
  float* kb  = (float*)(ws + 16 * MB);
  float* vb  = (float*)(ws + 32 * MB);
  float* gb  = (float*)(ws + 48 * MB);
  float* st  = (float*)(ws + 56 * MB);
  float* gcb = (float*)(ws + 88 * MB);
  float* ob  = (float*)(ws + 89 * MB);
  unsigned short* xb    = (unsigned short*)(ws + 56 * MB);
  unsigned short* wqkvf = (unsigned short*)(ws + 64 * MB);
  unsigned short* wob   = (unsigned short*)(ws + 105 * MB);
  unsigned short* nbb   = (unsigned short*)(ws); // alias qb

  dim3 blk(256);
  cvt_bf16_all<<<dim3(4352), blk, 0, stream>>>(x, Wq, Wk, Wv, Wf, Wo, xb, wqkvf, wob);
  gemm_bt<1><<<dim3(28, 32), blk, 0, stream>>>(xb, wqkvf, qb, kb, vb, gb);
  scan_phase1<<<dim3(NC, 16), blk, 0, stream>>>(kb, vb, gb, st, gcb);
  scan_phase2<<<dim3(16, 16), blk, 0, stream>>>(st, gcb);
  scan_phase3<<<dim3(NC, 16), blk, 0, stream>>>(qb, kb, vb, gb, st, ob);
  post_rms<<<dim3(ROWS), blk, 0, stream>>>(ob, gw, nbb);
  gemm_bt<0><<<dim3(8, 32), blk, 0, stream>>>(nbb, wob, out, nullptr, nullptr, nullptr);
}